// Round 6
// baseline (104.461 us; speedup 1.0000x reference)
//
#include <hip/hip_runtime.h>

#define NODES 4096
#define NDIM  512
#define HID   4096

typedef __attribute__((ext_vector_type(8))) short bf16x8;
typedef __attribute__((ext_vector_type(4))) float f32x4;

__device__ __forceinline__ float b2f(short v) {
  union { unsigned int u; float f; } c;
  c.u = ((unsigned int)(unsigned short)v) << 16;
  return c.f;
}
__device__ __forceinline__ short f2b(float f) {
  union { float f; unsigned int u; } c; c.f = f;
  unsigned int r = c.u + 0x7fffu + ((c.u >> 16) & 1u);  // round-nearest-even
  return (short)(r >> 16);
}

// ---- K0: fused prep: cast x->bf16 | transpose+cast W1 | init accumulators ----
__global__ __launch_bounds__(256) void k_prep(const float* __restrict__ x,
                                              const float* __restrict__ W1,
                                              const float* __restrict__ b2,
                                              const float* __restrict__ b3,
                                              short* __restrict__ xb,
                                              short* __restrict__ w1t,
                                              float* __restrict__ aacc,
                                              float* __restrict__ svec,
                                              float* __restrict__ uacc) {
  __shared__ float tile[32][33];
  int b = blockIdx.x;
  if (b < 2048) {                       // cast x (4096x512 fp32 -> bf16)
    int i = (b * 256 + threadIdx.x) * 4;
    float4 v = *(const float4*)(x + i);
    short4 o;
    o.x = f2b(v.x); o.y = f2b(v.y); o.z = f2b(v.z); o.w = f2b(v.w);
    *(short4*)(xb + i) = o;
  } else if (b < 4096) {                // transpose W1 [512][4096] -> [4096][512] bf16
    int t = b - 2048;
    int n0 = (t & 127) * 32;
    int k0 = (t >> 7) * 32;
    int tx = threadIdx.x & 31, ty = threadIdx.x >> 5;
    #pragma unroll
    for (int j = 0; j < 4; ++j) {
      int kk = ty + j * 8;
      tile[kk][tx] = W1[(size_t)(k0 + kk) * HID + n0 + tx];
    }
    __syncthreads();
    #pragma unroll
    for (int j = 0; j < 4; ++j) {
      int nn = ty + j * 8;
      w1t[(size_t)(n0 + nn) * NDIM + k0 + tx] = f2b(tile[tx][nn]);
    }
  } else {                              // init: a=0, s=N*b2, u=b3
    int j = (b - 4096) * 256 + threadIdx.x;
    aacc[j] = 0.0f;
    svec[j] = (float)NODES * b2[j];
    uacc[j] = b3[j];
  }
}

// ---- K1: A = relu(x @ W1 + b1) (bf16 MFMA), fused column sums ----
// 128x128 tile, BK=32, LINEAR dbuf LDS (proven R4 loop) + counted vmcnt(4).
// Operand-swapped MFMA -> C^T fragments -> packed short4 (8 B) stores.
__global__ __launch_bounds__(256) void k_gemm1(const short* __restrict__ xb,
                                               const short* __restrict__ w1t,
                                               const float* __restrict__ b1,
                                               short* __restrict__ Aout,
                                               float* __restrict__ colsum) {
  __shared__ short smem[16384];         // 32 KB: A dbuf @0, B dbuf @16384 B
  __shared__ float csum[128];

  const int tid  = threadIdx.x;
  const int lane = tid & 63;
  const int w    = tid >> 6;
  const int wr   = w >> 1, wc = w & 1;

  // XCD-aware swizzle (1024 blocks, %8==0 -> simple bijective form)
  int bswz = (blockIdx.x & 7) * 128 + (blockIdx.x >> 3);
  const int brow = (bswz >> 5) * 128, bcol = (bswz & 31) * 128;

  f32x4 acc[4][4];
  #pragma unroll
  for (int i = 0; i < 4; ++i)
    #pragma unroll
    for (int j = 0; j < 4; ++j)
      acc[i][j] = (f32x4){0.f, 0.f, 0.f, 0.f};

  if (tid < 128) csum[tid] = 0.f;

  const int fr = lane & 15;
  const int fk = (lane >> 4) * 8;       // 8 consecutive k per lane (shorts)

  // hoisted staging addresses (advance by kt*32 shorts per K-step)
  const int off0 = w * 1024 + lane * 16;          // j=0 byte offset in 8 KB tile
  const int off1 = off0 + 4096;                   // j=1
  const int row0 = off0 >> 6, ce0 = (off0 & 63) >> 1;
  const int row1 = off1 >> 6, ce1 = (off1 & 63) >> 1;
  const short* gA0 = xb  + (size_t)(brow + row0) * NDIM + ce0;
  const short* gA1 = xb  + (size_t)(brow + row1) * NDIM + ce1;
  const short* gB0 = w1t + (size_t)(bcol + row0) * NDIM + ce0;
  const short* gB1 = w1t + (size_t)(bcol + row1) * NDIM + ce1;

  // Exactly 4 global_load_lds per wave per call.
  auto STAGE = [&](int buf, int kt) {
    char* base = (char*)smem + buf * 8192;
    __builtin_amdgcn_global_load_lds(
        (const __attribute__((address_space(1))) void*)(gA0 + kt * 32),
        (__attribute__((address_space(3))) void*)(base + off0), 16, 0, 0);
    __builtin_amdgcn_global_load_lds(
        (const __attribute__((address_space(1))) void*)(gA1 + kt * 32),
        (__attribute__((address_space(3))) void*)(base + off1), 16, 0, 0);
    __builtin_amdgcn_global_load_lds(
        (const __attribute__((address_space(1))) void*)(gB0 + kt * 32),
        (__attribute__((address_space(3))) void*)(base + 16384 + off0), 16, 0, 0);
    __builtin_amdgcn_global_load_lds(
        (const __attribute__((address_space(1))) void*)(gB1 + kt * 32),
        (__attribute__((address_space(3))) void*)(base + 16384 + off1), 16, 0, 0);
  };

  auto COMPUTE = [&](int buf) {
    bf16x8 af[4], bfr[4];
    const short* Ab = (const short*)((char*)smem + buf * 8192);
    const short* Bb = (const short*)((char*)smem + 16384 + buf * 8192);
    #pragma unroll
    for (int mi = 0; mi < 4; ++mi)
      af[mi] = *(const bf16x8*)(Ab + (wr * 64 + mi * 16 + fr) * 32 + fk);
    #pragma unroll
    for (int ni = 0; ni < 4; ++ni)
      bfr[ni] = *(const bf16x8*)(Bb + (wc * 64 + ni * 16 + fr) * 32 + fk);
    // swapped operands: acc[mi][ni] = C^T fragment
    // value(lane,reg) = C[row = mi*16 + (lane&15)][col = ni*16 + (lane>>4)*4 + reg]
    #pragma unroll
    for (int mi = 0; mi < 4; ++mi)
      #pragma unroll
      for (int ni = 0; ni < 4; ++ni)
        acc[mi][ni] = __builtin_amdgcn_mfma_f32_16x16x32_bf16(bfr[ni], af[mi],
                                                              acc[mi][ni], 0, 0, 0);
  };

  STAGE(0, 0);                                     // 4 VMEM in flight (tile 0)
  #pragma unroll 1
  for (int kt = 0; kt < NDIM / 32 - 1; ++kt) {
    STAGE((kt + 1) & 1, kt + 1);                   // +4 VMEM (tile kt+1)
    asm volatile("s_waitcnt vmcnt(4)" ::: "memory");  // tile kt landed; kt+1 in flight
    __builtin_amdgcn_s_barrier();                  // all waves: tile kt visible
    COMPUTE(kt & 1);
    __builtin_amdgcn_s_barrier();                  // all waves done reading buf kt&1
  }
  asm volatile("s_waitcnt vmcnt(0)" ::: "memory"); // last tile landed
  __builtin_amdgcn_s_barrier();
  COMPUTE((NDIM / 32 - 1) & 1);

  // epilogue: bias + relu + packed short4 stores + shuffle-reduced column sums
  const int cr = lane & 15;            // output row within 16-frag
  const int cg = (lane >> 4) * 4;      // output col base within 16-frag
  float4 bias4[4];
  #pragma unroll
  for (int ni = 0; ni < 4; ++ni)
    bias4[ni] = *(const float4*)(b1 + bcol + wc * 64 + ni * 16 + cg);

  float cl[4][4];
  #pragma unroll
  for (int ni = 0; ni < 4; ++ni)
    #pragma unroll
    for (int r = 0; r < 4; ++r)
      cl[ni][r] = 0.f;

  #pragma unroll
  for (int mi = 0; mi < 4; ++mi) {
    int grow = brow + wr * 64 + mi * 16 + cr;
    short* orow = Aout + (size_t)grow * HID + bcol + wc * 64;
    #pragma unroll
    for (int ni = 0; ni < 4; ++ni) {
      float v0 = fmaxf(acc[mi][ni][0] + bias4[ni].x, 0.f);
      float v1 = fmaxf(acc[mi][ni][1] + bias4[ni].y, 0.f);
      float v2 = fmaxf(acc[mi][ni][2] + bias4[ni].z, 0.f);
      float v3 = fmaxf(acc[mi][ni][3] + bias4[ni].w, 0.f);
      cl[ni][0] += v0; cl[ni][1] += v1; cl[ni][2] += v2; cl[ni][3] += v3;
      short4 o;
      o.x = f2b(v0); o.y = f2b(v1); o.z = f2b(v2); o.w = f2b(v3);
      *(short4*)(orow + ni * 16 + cg) = o;
    }
  }
  // sum over the 16 rows (lanes sharing lane>>4) via xor-butterfly on low 4 bits
  #pragma unroll
  for (int ni = 0; ni < 4; ++ni)
    #pragma unroll
    for (int r = 0; r < 4; ++r) {
      #pragma unroll
      for (int m = 1; m < 16; m <<= 1)
        cl[ni][r] += __shfl_xor(cl[ni][r], m);
    }
  if (cr == 0) {                       // 4 lanes/wave; wr=0/1 -> 2-way contention
    #pragma unroll
    for (int ni = 0; ni < 4; ++ni)
      #pragma unroll
      for (int r = 0; r < 4; ++r)
        atomicAdd(&csum[wc * 64 + ni * 16 + cg + r], cl[ni][r]);
  }
  __syncthreads();
  if (tid < 128) atomicAdd(&colsum[bcol + tid], csum[tid]);
}

// ---- K2/K5: vout[col] += sum_i vin[i] * W[i][col]  (W: [4096][4096] fp32) ----
__global__ __launch_bounds__(256) void k_gemv_at(const float* __restrict__ W,
                                                 const float* __restrict__ vin,
                                                 float* __restrict__ vout) {
  const int col = blockIdx.x * 1024 + threadIdx.x * 4;
  const int r0  = blockIdx.y * 64;
  float4 accv = {0.f, 0.f, 0.f, 0.f};
  const float* base = W + (size_t)r0 * HID + col;
  #pragma unroll 16
  for (int i = 0; i < 64; ++i) {
    float vi = vin[r0 + i];
    float4 wv = *(const float4*)(base + (size_t)i * HID);
    accv.x += vi * wv.x; accv.y += vi * wv.y;
    accv.z += vi * wv.z; accv.w += vi * wv.w;
  }
  atomicAdd(&vout[col + 0], accv.x);
  atomicAdd(&vout[col + 1], accv.y);
  atomicAdd(&vout[col + 2], accv.z);
  atomicAdd(&vout[col + 3], accv.w);
}

// ---- K3: t[row] = W2[row,:] . s ; extra block computes beta = b2 . s ----
__global__ __launch_bounds__(256) void k_gemv_row(const float* __restrict__ W,
                                                  const float* __restrict__ vin,
                                                  const float* __restrict__ b2,
                                                  float* __restrict__ vout,
                                                  float* __restrict__ beta) {
  __shared__ float red[4];
  if (blockIdx.x == HID / 4) {           // beta block
    float p = 0.f;
    for (int j = threadIdx.x; j < HID; j += 256) p += b2[j] * vin[j];
    #pragma unroll
    for (int o = 32; o > 0; o >>= 1) p += __shfl_down(p, o);
    int lane = threadIdx.x & 63, w = threadIdx.x >> 6;
    if (lane == 0) red[w] = p;
    __syncthreads();
    if (threadIdx.x == 0) beta[0] = red[0] + red[1] + red[2] + red[3];
    return;
  }
  int w = threadIdx.x >> 6, lane = threadIdx.x & 63;
  int row = blockIdx.x * 4 + w;
  const float* base = W + (size_t)row * HID;
  float p = 0.f;
  #pragma unroll 8
  for (int j = lane * 4; j < HID; j += 256) {
    float4 wv = *(const float4*)(base + j);
    float4 sv = *(const float4*)(vin + j);
    p += wv.x * sv.x + wv.y * sv.y + wv.z * sv.z + wv.w * sv.w;
  }
  #pragma unroll
  for (int o = 32; o > 0; o >>= 1) p += __shfl_down(p, o);
  if (lane == 0) vout[row] = p;
}

// ---- K4: kv[row] = A[row,:] . t + beta   (A bf16) ----
__global__ __launch_bounds__(256) void k_kv(const short* __restrict__ A,
                                            const float* __restrict__ t,
                                            const float* __restrict__ beta,
                                            float* __restrict__ kv) {
  int w = threadIdx.x >> 6, lane = threadIdx.x & 63;
  int row = blockIdx.x * 4 + w;
  const short* base = A + (size_t)row * HID;
  float p = 0.f;
  #pragma unroll
  for (int j = lane * 8; j < HID; j += 512) {
    bf16x8 av = *(const bf16x8*)(base + j);
    float4 t0 = *(const float4*)(t + j);
    float4 t1 = *(const float4*)(t + j + 4);
    p += b2f(av[0]) * t0.x + b2f(av[1]) * t0.y + b2f(av[2]) * t0.z + b2f(av[3]) * t0.w
       + b2f(av[4]) * t1.x + b2f(av[5]) * t1.y + b2f(av[6]) * t1.z + b2f(av[7]) * t1.w;
  }
  #pragma unroll
  for (int o = 32; o > 0; o >>= 1) p += __shfl_down(p, o);
  if (lane == 0) kv[row] = p + beta[0];
}

// ---- K6: out = relu(uacc) . W4 + b4 ----
__global__ __launch_bounds__(256) void k_final(const float* __restrict__ uacc,
                                               const float* __restrict__ W4,
                                               const float* __restrict__ b4,
                                               float* __restrict__ out) {
  __shared__ float red[4];
  float p = 0.f;
  for (int j = threadIdx.x; j < HID; j += 256) {
    float uv = uacc[j];
    uv = uv > 0.f ? uv : 0.f;
    p += uv * W4[j];
  }
  #pragma unroll
  for (int o = 32; o > 0; o >>= 1) p += __shfl_down(p, o);
  int lane = threadIdx.x & 63, w = threadIdx.x >> 6;
  if (lane == 0) red[w] = p;
  __syncthreads();
  if (threadIdx.x == 0) out[0] = red[0] + red[1] + red[2] + red[3] + b4[0];
}

extern "C" void kernel_launch(void* const* d_in, const int* in_sizes, int n_in,
                              void* d_out, int out_size, void* d_ws, size_t ws_size,
                              hipStream_t stream) {
  const float* x  = (const float*)d_in[0];
  // d_in[1] = edge_index (dead in the reference)
  const float* W1 = (const float*)d_in[2];
  const float* b1 = (const float*)d_in[3];
  const float* W2 = (const float*)d_in[4];
  const float* b2 = (const float*)d_in[5];
  const float* W3 = (const float*)d_in[6];
  const float* b3 = (const float*)d_in[7];
  const float* W4 = (const float*)d_in[8];
  const float* b4 = (const float*)d_in[9];
  float* out = (float*)d_out;

  char* ws = (char*)d_ws;
  short* Abf  = (short*)(ws);                 // 32 MB
  short* xb   = (short*)(ws + 33554432);      // 4 MB
  short* w1t  = (short*)(ws + 37748736);      // 4 MB
  float* aacc = (float*)(ws + 41943040);
  float* svec = (float*)(ws + 41959424);
  float* tvec = (float*)(ws + 41975808);
  float* kvv  = (float*)(ws + 41992192);
  float* uacc = (float*)(ws + 42008576);
  float* beta = (float*)(ws + 42024960);

  k_prep    <<<dim3(4112),     dim3(256), 0, stream>>>(x, W1, b2, b3, xb, w1t, aacc, svec, uacc);
  k_gemm1   <<<dim3(1024),     dim3(256), 0, stream>>>(xb, w1t, b1, Abf, aacc);
  k_gemv_at <<<dim3(4, 64),    dim3(256), 0, stream>>>(W2, aacc, svec);
  k_gemv_row<<<dim3(1025),     dim3(256), 0, stream>>>(W2, svec, b2, tvec, beta);
  k_kv      <<<dim3(1024),     dim3(256), 0, stream>>>(Abf, tvec, beta, kvv);
  k_gemv_at <<<dim3(4, 64),    dim3(256), 0, stream>>>(W3, kvv, uacc);
  k_final   <<<dim3(1),        dim3(256), 0, stream>>>(uacc, W4, b4, out);
}

// Round 8
// 104.279 us; speedup vs baseline: 1.0017x; 1.0017x over previous
//
#include <hip/hip_runtime.h>

#define NODES 4096
#define NDIM  512
#define HID   4096

typedef __attribute__((ext_vector_type(8))) short bf16x8;
typedef __attribute__((ext_vector_type(4))) float f32x4;

__device__ __forceinline__ float b2f(short v) {
  union { unsigned int u; float f; } c;
  c.u = ((unsigned int)(unsigned short)v) << 16;
  return c.f;
}
__device__ __forceinline__ short f2b(float f) {
  union { float f; unsigned int u; } c; c.f = f;
  unsigned int r = c.u + 0x7fffu + ((c.u >> 16) & 1u);  // round-nearest-even
  return (short)(r >> 16);
}

// ---- K0: fused prep: cast x->bf16 | transpose+cast W1 | init accumulators ----
__global__ __launch_bounds__(256) void k_prep(const float* __restrict__ x,
                                              const float* __restrict__ W1,
                                              const float* __restrict__ b2,
                                              const float* __restrict__ b3,
                                              short* __restrict__ xb,
                                              short* __restrict__ w1t,
                                              float* __restrict__ aacc,
                                              float* __restrict__ svec,
                                              float* __restrict__ uacc) {
  __shared__ float tile[32][33];
  int b = blockIdx.x;
  if (b < 2048) {                       // cast x (4096x512 fp32 -> bf16)
    int i = (b * 256 + threadIdx.x) * 4;
    float4 v = *(const float4*)(x + i);
    short4 o;
    o.x = f2b(v.x); o.y = f2b(v.y); o.z = f2b(v.z); o.w = f2b(v.w);
    *(short4*)(xb + i) = o;
  } else if (b < 4096) {                // transpose W1 [512][4096] -> [4096][512] bf16
    int t = b - 2048;
    int n0 = (t & 127) * 32;
    int k0 = (t >> 7) * 32;
    int tx = threadIdx.x & 31, ty = threadIdx.x >> 5;
    #pragma unroll
    for (int j = 0; j < 4; ++j) {
      int kk = ty + j * 8;
      tile[kk][tx] = W1[(size_t)(k0 + kk) * HID + n0 + tx];
    }
    __syncthreads();
    #pragma unroll
    for (int j = 0; j < 4; ++j) {
      int nn = ty + j * 8;
      w1t[(size_t)(n0 + nn) * NDIM + k0 + tx] = f2b(tile[tx][nn]);
    }
  } else {                              // init: a=0, s=N*b2, u=b3
    int j = (b - 4096) * 256 + threadIdx.x;
    aacc[j] = 0.0f;
    svec[j] = (float)NODES * b2[j];
    uacc[j] = b3[j];
  }
}

// ---- K1: A = relu(x @ W1 + b1) (bf16 MFMA), fused column sums ----
// 128x128 tile, BK=32, TRI-buffered LDS (depth-2 prefetch, vmcnt(8)).
// A bufs at bytes 0/8K/16K; B bufs at bytes 24K/32K/40K (24576 + buf*8192).
__global__ __launch_bounds__(256) void k_gemm1(const short* __restrict__ xb,
                                               const short* __restrict__ w1t,
                                               const float* __restrict__ b1,
                                               short* __restrict__ Aout,
                                               float* __restrict__ colsum) {
  __shared__ short smem[24576];         // 48 KB total
  __shared__ float csum[128];

  const int tid  = threadIdx.x;
  const int lane = tid & 63;
  const int w    = tid >> 6;
  const int wr   = w >> 1, wc = w & 1;

  // XCD-aware swizzle (1024 blocks, %8==0 -> simple bijective form)
  int bswz = (blockIdx.x & 7) * 128 + (blockIdx.x >> 3);
  const int brow = (bswz >> 5) * 128, bcol = (bswz & 31) * 128;

  f32x4 acc[4][4];
  #pragma unroll
  for (int i = 0; i < 4; ++i)
    #pragma unroll
    for (int j = 0; j < 4; ++j)
      acc[i][j] = (f32x4){0.f, 0.f, 0.f, 0.f};

  if (tid < 128) csum[tid] = 0.f;

  const int fr = lane & 15;
  const int fk = (lane >> 4) * 8;       // 8 consecutive k per lane (shorts)

  // hoisted staging addresses (advance by kt*32 shorts per K-step)
  const int off0 = w * 1024 + lane * 16;          // j=0 byte offset in 8 KB tile
  const int off1 = off0 + 4096;                   // j=1
  const int row0 = off0 >> 6, ce0 = (off0 & 63) >> 1;
  const int row1 = off1 >> 6, ce1 = (off1 & 63) >> 1;
  const short* gA0 = xb  + (size_t)(brow + row0) * NDIM + ce0;
  const short* gA1 = xb  + (size_t)(brow + row1) * NDIM + ce1;
  const short* gB0 = w1t + (size_t)(bcol + row0) * NDIM + ce0;
  const short* gB1 = w1t + (size_t)(bcol + row1) * NDIM + ce1;

  // Exactly 4 global_load_lds per wave per call.
  auto STAGE = [&](int buf, int kt) {
    char* baseA = (char*)smem + buf * 8192;           // bytes 0..24575
    char* baseB = (char*)smem + 24576 + buf * 8192;   // bytes 24576..49151
    __builtin_amdgcn_global_load_lds(
        (const __attribute__((address_space(1))) void*)(gA0 + kt * 32),
        (__attribute__((address_space(3))) void*)(baseA + off0), 16, 0, 0);
    __builtin_amdgcn_global_load_lds(
        (const __attribute__((address_space(1))) void*)(gA1 + kt * 32),
        (__attribute__((address_space(3))) void*)(baseA + off1), 16, 0, 0);
    __builtin_amdgcn_global_load_lds(
        (const __attribute__((address_space(1))) void*)(gB0 + kt * 32),
        (__attribute__((address_space(3))) void*)(baseB + off0), 16, 0, 0);
    __builtin_amdgcn_global_load_lds(
        (const __attribute__((address_space(1))) void*)(gB1 + kt * 32),
        (__attribute__((address_space(3))) void*)(baseB + off1), 16, 0, 0);
  };

  auto COMPUTE = [&](int buf) {
    bf16x8 af[4], bfr[4];
    const short* Ab = (const short*)((char*)smem + buf * 8192);
    const short* Bb = (const short*)((char*)smem + 24576 + buf * 8192);
    #pragma unroll
    for (int mi = 0; mi < 4; ++mi)
      af[mi] = *(const bf16x8*)(Ab + (wr * 64 + mi * 16 + fr) * 32 + fk);
    #pragma unroll
    for (int ni = 0; ni < 4; ++ni)
      bfr[ni] = *(const bf16x8*)(Bb + (wc * 64 + ni * 16 + fr) * 32 + fk);
    // swapped operands: acc[mi][ni] = C^T fragment
    // value(lane,reg) = C[row = mi*16 + (lane&15)][col = ni*16 + (lane>>4)*4 + reg]
    #pragma unroll
    for (int mi = 0; mi < 4; ++mi)
      #pragma unroll
      for (int ni = 0; ni < 4; ++ni)
        acc[mi][ni] = __builtin_amdgcn_mfma_f32_16x16x32_bf16(bfr[ni], af[mi],
                                                              acc[mi][ni], 0, 0, 0);
  };

  STAGE(0, 0);                                     // tiles 0,1 in flight (8 VMEM)
  STAGE(1, 1);
  int cur = 0, nxt = 1, fut = 2;
  #pragma unroll 1
  for (int kt = 0; kt < NDIM / 32 - 2; ++kt) {     // kt = 0..13
    STAGE(fut, kt + 2);                            // 12 VMEM in flight
    asm volatile("s_waitcnt vmcnt(8)" ::: "memory");  // tile kt landed; kt+1,kt+2 fly
    __builtin_amdgcn_s_barrier();                  // all waves: tile kt visible
    COMPUTE(cur);
    __builtin_amdgcn_s_barrier();                  // all done reading buf cur
    int t = cur; cur = nxt; nxt = fut; fut = t;
  }
  asm volatile("s_waitcnt vmcnt(4)" ::: "memory"); // tile 14 landed; 15 in flight
  __builtin_amdgcn_s_barrier();
  COMPUTE(cur);
  asm volatile("s_waitcnt vmcnt(0)" ::: "memory"); // tile 15 landed
  __builtin_amdgcn_s_barrier();
  COMPUTE(nxt);

  // epilogue: bias + relu + packed short4 stores + shuffle-reduced column sums
  const int cr = lane & 15;            // output row within 16-frag
  const int cg = (lane >> 4) * 4;      // output col base within 16-frag
  float4 bias4[4];
  #pragma unroll
  for (int ni = 0; ni < 4; ++ni)
    bias4[ni] = *(const float4*)(b1 + bcol + wc * 64 + ni * 16 + cg);

  float cl[4][4];
  #pragma unroll
  for (int ni = 0; ni < 4; ++ni)
    #pragma unroll
    for (int r = 0; r < 4; ++r)
      cl[ni][r] = 0.f;

  #pragma unroll
  for (int mi = 0; mi < 4; ++mi) {
    int grow = brow + wr * 64 + mi * 16 + cr;
    short* orow = Aout + (size_t)grow * HID + bcol + wc * 64;
    #pragma unroll
    for (int ni = 0; ni < 4; ++ni) {
      float v0 = fmaxf(acc[mi][ni][0] + bias4[ni].x, 0.f);
      float v1 = fmaxf(acc[mi][ni][1] + bias4[ni].y, 0.f);
      float v2 = fmaxf(acc[mi][ni][2] + bias4[ni].z, 0.f);
      float v3 = fmaxf(acc[mi][ni][3] + bias4[ni].w, 0.f);
      cl[ni][0] += v0; cl[ni][1] += v1; cl[ni][2] += v2; cl[ni][3] += v3;
      short4 o;
      o.x = f2b(v0); o.y = f2b(v1); o.z = f2b(v2); o.w = f2b(v3);
      *(short4*)(orow + ni * 16 + cg) = o;
    }
  }
  // sum over the 16 rows (lanes sharing lane>>4) via xor-butterfly on low 4 bits
  #pragma unroll
  for (int ni = 0; ni < 4; ++ni)
    #pragma unroll
    for (int r = 0; r < 4; ++r) {
      #pragma unroll
      for (int m = 1; m < 16; m <<= 1)
        cl[ni][r] += __shfl_xor(cl[ni][r], m);
    }
  if (cr == 0) {                       // 4 lanes/wave; wr=0/1 -> 2-way contention
    #pragma unroll
    for (int ni = 0; ni < 4; ++ni)
      #pragma unroll
      for (int r = 0; r < 4; ++r)
        atomicAdd(&csum[wc * 64 + ni * 16 + cg + r], cl[ni][r]);
  }
  __syncthreads();
  if (tid < 128) atomicAdd(&colsum[bcol + tid], csum[tid]);
}

// ---- K2/K5: vout[col] += sum_i vin[i] * W[i][col]  (W: [4096][4096] fp32) ----
__global__ __launch_bounds__(256) void k_gemv_at(const float* __restrict__ W,
                                                 const float* __restrict__ vin,
                                                 float* __restrict__ vout) {
  const int col = blockIdx.x * 1024 + threadIdx.x * 4;
  const int r0  = blockIdx.y * 64;
  float4 accv = {0.f, 0.f, 0.f, 0.f};
  const float* base = W + (size_t)r0 * HID + col;
  #pragma unroll 16
  for (int i = 0; i < 64; ++i) {
    float vi = vin[r0 + i];
    float4 wv = *(const float4*)(base + (size_t)i * HID);
    accv.x += vi * wv.x; accv.y += vi * wv.y;
    accv.z += vi * wv.z; accv.w += vi * wv.w;
  }
  atomicAdd(&vout[col + 0], accv.x);
  atomicAdd(&vout[col + 1], accv.y);
  atomicAdd(&vout[col + 2], accv.z);
  atomicAdd(&vout[col + 3], accv.w);
}

// ---- K3: t[row] = W2[row,:] . s ; extra block computes beta = b2 . s ----
__global__ __launch_bounds__(256) void k_gemv_row(const float* __restrict__ W,
                                                  const float* __restrict__ vin,
                                                  const float* __restrict__ b2,
                                                  float* __restrict__ vout,
                                                  float* __restrict__ beta) {
  __shared__ float red[4];
  if (blockIdx.x == HID / 4) {           // beta block
    float p = 0.f;
    for (int j = threadIdx.x; j < HID; j += 256) p += b2[j] * vin[j];
    #pragma unroll
    for (int o = 32; o > 0; o >>= 1) p += __shfl_down(p, o);
    int lane = threadIdx.x & 63, w = threadIdx.x >> 6;
    if (lane == 0) red[w] = p;
    __syncthreads();
    if (threadIdx.x == 0) beta[0] = red[0] + red[1] + red[2] + red[3];
    return;
  }
  int w = threadIdx.x >> 6, lane = threadIdx.x & 63;
  int row = blockIdx.x * 4 + w;
  const float* base = W + (size_t)row * HID;
  float p = 0.f;
  #pragma unroll 8
  for (int j = lane * 4; j < HID; j += 256) {
    float4 wv = *(const float4*)(base + j);
    float4 sv = *(const float4*)(vin + j);
    p += wv.x * sv.x + wv.y * sv.y + wv.z * sv.z + wv.w * sv.w;
  }
  #pragma unroll
  for (int o = 32; o > 0; o >>= 1) p += __shfl_down(p, o);
  if (lane == 0) vout[row] = p;
}

// ---- K4: kv[row] = A[row,:] . t + beta   (A bf16) ----
__global__ __launch_bounds__(256) void k_kv(const short* __restrict__ A,
                                            const float* __restrict__ t,
                                            const float* __restrict__ beta,
                                            float* __restrict__ kv) {
  int w = threadIdx.x >> 6, lane = threadIdx.x & 63;
  int row = blockIdx.x * 4 + w;
  const short* base = A + (size_t)row * HID;
  float p = 0.f;
  #pragma unroll
  for (int j = lane * 8; j < HID; j += 512) {
    bf16x8 av = *(const bf16x8*)(base + j);
    float4 t0 = *(const float4*)(t + j);
    float4 t1 = *(const float4*)(t + j + 4);
    p += b2f(av[0]) * t0.x + b2f(av[1]) * t0.y + b2f(av[2]) * t0.z + b2f(av[3]) * t0.w
       + b2f(av[4]) * t1.x + b2f(av[5]) * t1.y + b2f(av[6]) * t1.z + b2f(av[7]) * t1.w;
  }
  #pragma unroll
  for (int o = 32; o > 0; o >>= 1) p += __shfl_down(p, o);
  if (lane == 0) kv[row] = p + beta[0];
}

// ---- K6: out = relu(uacc) . W4 + b4 ----
__global__ __launch_bounds__(256) void k_final(const float* __restrict__ uacc,
                                               const float* __restrict__ W4,
                                               const float* __restrict__ b4,
                                               float* __restrict__ out) {
  __shared__ float red[4];
  float p = 0.f;
  for (int j = threadIdx.x; j < HID; j += 256) {
    float uv = uacc[j];
    uv = uv > 0.f ? uv : 0.f;
    p += uv * W4[j];
  }
  #pragma unroll
  for (int o = 32; o > 0; o >>= 1) p += __shfl_down(p, o);
  int lane = threadIdx.x & 63, w = threadIdx.x >> 6;
  if (lane == 0) red[w] = p;
  __syncthreads();
  if (threadIdx.x == 0) out[0] = red[0] + red[1] + red[2] + red[3] + b4[0];
}

extern "C" void kernel_launch(void* const* d_in, const int* in_sizes, int n_in,
                              void* d_out, int out_size, void* d_ws, size_t ws_size,
                              hipStream_t stream) {
  const float* x  = (const float*)d_in[0];
  // d_in[1] = edge_index (dead in the reference)
  const float* W1 = (const float*)d_in[2];
  const float* b1 = (const float*)d_in[3];
  const float* W2 = (const float*)d_in[4];
  const float* b2 = (const float*)d_in[5];
  const float* W3 = (const float*)d_in[6];
  const float* b3 = (const float*)d_in[7];
  const float* W4 = (const float*)d_in[8];
  const float* b4 = (const float*)d_in[9];
  float* out = (float*)d_out;

  char* ws = (char*)d_ws;
  short* Abf  = (short*)(ws);                 // 32 MB
  short* xb   = (short*)(ws + 33554432);      // 4 MB
  short* w1t  = (short*)(ws + 37748736);      // 4 MB
  float* aacc = (float*)(ws + 41943040);
  float* svec = (float*)(ws + 41959424);
  float* tvec = (float*)(ws + 41975808);
  float* kvv  = (float*)(ws + 41992192);
  float* uacc = (float*)(ws + 42008576);
  float* beta = (float*)(ws + 42024960);

  k_prep    <<<dim3(4112),     dim3(256), 0, stream>>>(x, W1, b2, b3, xb, w1t, aacc, svec, uacc);
  k_gemm1   <<<dim3(1024),     dim3(256), 0, stream>>>(xb, w1t, b1, Abf, aacc);
  k_gemv_at <<<dim3(4, 64),    dim3(256), 0, stream>>>(W2, aacc, svec);
  k_gemv_row<<<dim3(1025),     dim3(256), 0, stream>>>(W2, svec, b2, tvec, beta);
  k_kv      <<<dim3(1024),     dim3(256), 0, stream>>>(Abf, tvec, beta, kvv);
  k_gemv_at <<<dim3(4, 64),    dim3(256), 0, stream>>>(W3, kvv, uacc);
  k_final   <<<dim3(1),        dim3(256), 0, stream>>>(uacc, W4, b4, out);
}

// Round 9
// 97.635 us; speedup vs baseline: 1.0699x; 1.0680x over previous
//
#include <hip/hip_runtime.h>

#define NODES 4096
#define NDIM  512
#define HID   4096

typedef __attribute__((ext_vector_type(8))) short bf16x8;
typedef __attribute__((ext_vector_type(4))) float f32x4;

__device__ __forceinline__ float b2f(short v) {
  union { unsigned int u; float f; } c;
  c.u = ((unsigned int)(unsigned short)v) << 16;
  return c.f;
}
__device__ __forceinline__ short f2b(float f) {
  union { float f; unsigned int u; } c; c.f = f;
  unsigned int r = c.u + 0x7fffu + ((c.u >> 16) & 1u);  // round-nearest-even
  return (short)(r >> 16);
}

// ---- K0: fused prep: cast x->bf16 | transpose+cast W1 | init accumulators ----
__global__ __launch_bounds__(256) void k_prep(const float* __restrict__ x,
                                              const float* __restrict__ W1,
                                              const float* __restrict__ b2,
                                              const float* __restrict__ b3,
                                              short* __restrict__ xb,
                                              short* __restrict__ w1t,
                                              float* __restrict__ aacc,
                                              float* __restrict__ svec,
                                              float* __restrict__ uacc) {
  __shared__ float tile[32][33];
  int b = blockIdx.x;
  if (b < 2048) {                       // cast x (4096x512 fp32 -> bf16)
    int i = (b * 256 + threadIdx.x) * 4;
    float4 v = *(const float4*)(x + i);
    short4 o;
    o.x = f2b(v.x); o.y = f2b(v.y); o.z = f2b(v.z); o.w = f2b(v.w);
    *(short4*)(xb + i) = o;
  } else if (b < 4096) {                // transpose W1 [512][4096] -> [4096][512] bf16
    int t = b - 2048;
    int n0 = (t & 127) * 32;
    int k0 = (t >> 7) * 32;
    int tx = threadIdx.x & 31, ty = threadIdx.x >> 5;
    #pragma unroll
    for (int j = 0; j < 4; ++j) {
      int kk = ty + j * 8;
      tile[kk][tx] = W1[(size_t)(k0 + kk) * HID + n0 + tx];
    }
    __syncthreads();
    #pragma unroll
    for (int j = 0; j < 4; ++j) {
      int nn = ty + j * 8;
      w1t[(size_t)(n0 + nn) * NDIM + k0 + tx] = f2b(tile[tx][nn]);
    }
  } else {                              // init: a=0, s=N*b2, u=b3
    int j = (b - 4096) * 256 + threadIdx.x;
    aacc[j] = 0.0f;
    svec[j] = (float)NODES * b2[j];
    uacc[j] = b3[j];
  }
}

// ---- K1: A = relu(x @ W1 + b1) (bf16 MFMA), fused column sums ----
// 256x256 tile, BK=32, 8 waves (2M x 4N, 128x64 per wave), dbuf LDS +
// counted vmcnt(4). Swapped-operand MFMA -> C^T frags -> packed short4 stores.
__global__ __launch_bounds__(512, 2) void k_gemm1(const short* __restrict__ xb,
                                                  const short* __restrict__ w1t,
                                                  const float* __restrict__ b1,
                                                  short* __restrict__ Aout,
                                                  float* __restrict__ colsum) {
  __shared__ short smem[32768];         // 64 KB: A bufs @0/16K, B bufs @32K/48K
  __shared__ float csum[256];

  const int tid  = threadIdx.x;
  const int lane = tid & 63;
  const int wid  = tid >> 6;            // 0..7
  const int wr   = wid >> 2;            // 0..1  (M)
  const int wc   = wid & 3;             // 0..3  (N)

  // XCD-aware swizzle (256 blocks, %8==0 -> simple bijective form)
  int bswz = (blockIdx.x & 7) * 32 + (blockIdx.x >> 3);
  const int brow = (bswz >> 4) * 256, bcol = (bswz & 15) * 256;

  f32x4 acc[8][4];
  #pragma unroll
  for (int i = 0; i < 8; ++i)
    #pragma unroll
    for (int j = 0; j < 4; ++j)
      acc[i][j] = (f32x4){0.f, 0.f, 0.f, 0.f};

  if (tid < 256) csum[tid] = 0.f;

  const int fr = lane & 15;
  const int fk = (lane >> 4) * 8;       // 8 consecutive k per lane (shorts)

  // staging addresses: tile is [256][32] shorts, row-major (64 B/row), LDS linear.
  // Each thread: 16 B at byte off0 (rows 0..127) and off0+8192 (rows 128..255).
  const int off0 = tid * 16;
  const int row0 = off0 >> 6, ce0 = (off0 & 63) >> 1;
  const short* gA0 = xb  + (size_t)(brow + row0) * NDIM + ce0;
  const short* gA1 = xb  + (size_t)(brow + row0 + 128) * NDIM + ce0;
  const short* gB0 = w1t + (size_t)(bcol + row0) * NDIM + ce0;
  const short* gB1 = w1t + (size_t)(bcol + row0 + 128) * NDIM + ce0;

  // Exactly 4 global_load_lds instructions per wave per call.
  auto STAGE = [&](int buf, int kt) {
    char* baseA = (char*)smem + buf * 16384;           // bytes 0..32767
    char* baseB = (char*)smem + 32768 + buf * 16384;   // bytes 32768..65535
    __builtin_amdgcn_global_load_lds(
        (const __attribute__((address_space(1))) void*)(gA0 + kt * 32),
        (__attribute__((address_space(3))) void*)(baseA + off0), 16, 0, 0);
    __builtin_amdgcn_global_load_lds(
        (const __attribute__((address_space(1))) void*)(gA1 + kt * 32),
        (__attribute__((address_space(3))) void*)(baseA + off0 + 8192), 16, 0, 0);
    __builtin_amdgcn_global_load_lds(
        (const __attribute__((address_space(1))) void*)(gB0 + kt * 32),
        (__attribute__((address_space(3))) void*)(baseB + off0), 16, 0, 0);
    __builtin_amdgcn_global_load_lds(
        (const __attribute__((address_space(1))) void*)(gB1 + kt * 32),
        (__attribute__((address_space(3))) void*)(baseB + off0 + 8192), 16, 0, 0);
  };

  auto COMPUTE = [&](int buf) {
    bf16x8 af[8], bfr[4];
    const short* Ab = (const short*)((char*)smem + buf * 16384);
    const short* Bb = (const short*)((char*)smem + 32768 + buf * 16384);
    #pragma unroll
    for (int ni = 0; ni < 4; ++ni)
      bfr[ni] = *(const bf16x8*)(Bb + (wc * 64 + ni * 16 + fr) * 32 + fk);
    #pragma unroll
    for (int mi = 0; mi < 8; ++mi)
      af[mi] = *(const bf16x8*)(Ab + (wr * 128 + mi * 16 + fr) * 32 + fk);
    // swapped operands: acc[mi][ni] = C^T fragment
    // value(lane,reg) = C[row = mi*16 + (lane&15)][col = ni*16 + (lane>>4)*4 + reg]
    #pragma unroll
    for (int mi = 0; mi < 8; ++mi)
      #pragma unroll
      for (int ni = 0; ni < 4; ++ni)
        acc[mi][ni] = __builtin_amdgcn_mfma_f32_16x16x32_bf16(bfr[ni], af[mi],
                                                              acc[mi][ni], 0, 0, 0);
  };

  STAGE(0, 0);                                     // 4 VMEM in flight (tile 0)
  #pragma unroll 1
  for (int kt = 0; kt < NDIM / 32 - 1; ++kt) {     // kt = 0..14
    STAGE((kt + 1) & 1, kt + 1);                   // +4 VMEM (tile kt+1)
    asm volatile("s_waitcnt vmcnt(4)" ::: "memory");  // tile kt landed; kt+1 in flight
    __builtin_amdgcn_s_barrier();                  // all waves: tile kt visible
    COMPUTE(kt & 1);
    __builtin_amdgcn_s_barrier();                  // all done reading buf kt&1
  }
  asm volatile("s_waitcnt vmcnt(0)" ::: "memory"); // last tile landed
  __builtin_amdgcn_s_barrier();
  COMPUTE((NDIM / 32 - 1) & 1);

  // epilogue: bias + relu + packed short4 stores + shuffle-reduced column sums
  const int cr = lane & 15;            // output row within 16-frag
  const int cg = (lane >> 4) * 4;      // output col base within 16-frag
  float4 bias4[4];
  #pragma unroll
  for (int ni = 0; ni < 4; ++ni)
    bias4[ni] = *(const float4*)(b1 + bcol + wc * 64 + ni * 16 + cg);

  float cl[4][4];
  #pragma unroll
  for (int ni = 0; ni < 4; ++ni)
    #pragma unroll
    for (int r = 0; r < 4; ++r)
      cl[ni][r] = 0.f;

  #pragma unroll
  for (int mi = 0; mi < 8; ++mi) {
    int grow = brow + wr * 128 + mi * 16 + cr;
    short* orow = Aout + (size_t)grow * HID + bcol + wc * 64;
    #pragma unroll
    for (int ni = 0; ni < 4; ++ni) {
      float v0 = fmaxf(acc[mi][ni][0] + bias4[ni].x, 0.f);
      float v1 = fmaxf(acc[mi][ni][1] + bias4[ni].y, 0.f);
      float v2 = fmaxf(acc[mi][ni][2] + bias4[ni].z, 0.f);
      float v3 = fmaxf(acc[mi][ni][3] + bias4[ni].w, 0.f);
      cl[ni][0] += v0; cl[ni][1] += v1; cl[ni][2] += v2; cl[ni][3] += v3;
      short4 o;
      o.x = f2b(v0); o.y = f2b(v1); o.z = f2b(v2); o.w = f2b(v3);
      *(short4*)(orow + ni * 16 + cg) = o;
    }
  }
  // sum over the 16 rows (lanes sharing lane>>4) via xor-butterfly on low 4 bits
  #pragma unroll
  for (int ni = 0; ni < 4; ++ni)
    #pragma unroll
    for (int r = 0; r < 4; ++r) {
      #pragma unroll
      for (int m = 1; m < 16; m <<= 1)
        cl[ni][r] += __shfl_xor(cl[ni][r], m);
    }
  if (cr == 0) {                       // 4 lanes/wave; wr=0/1 -> 2-way contention
    #pragma unroll
    for (int ni = 0; ni < 4; ++ni)
      #pragma unroll
      for (int r = 0; r < 4; ++r)
        atomicAdd(&csum[wc * 64 + ni * 16 + cg + r], cl[ni][r]);
  }
  __syncthreads();
  if (tid < 256) atomicAdd(&colsum[bcol + tid], csum[tid]);
}

// ---- K2/K5: vout[col] += sum_i vin[i] * W[i][col]  (W: [4096][4096] fp32) ----
__global__ __launch_bounds__(256) void k_gemv_at(const float* __restrict__ W,
                                                 const float* __restrict__ vin,
                                                 float* __restrict__ vout) {
  const int col = blockIdx.x * 1024 + threadIdx.x * 4;
  const int r0  = blockIdx.y * 64;
  float4 accv = {0.f, 0.f, 0.f, 0.f};
  const float* base = W + (size_t)r0 * HID + col;
  #pragma unroll 16
  for (int i = 0; i < 64; ++i) {
    float vi = vin[r0 + i];
    float4 wv = *(const float4*)(base + (size_t)i * HID);
    accv.x += vi * wv.x; accv.y += vi * wv.y;
    accv.z += vi * wv.z; accv.w += vi * wv.w;
  }
  atomicAdd(&vout[col + 0], accv.x);
  atomicAdd(&vout[col + 1], accv.y);
  atomicAdd(&vout[col + 2], accv.z);
  atomicAdd(&vout[col + 3], accv.w);
}

// ---- K3: t[row] = W2[row,:] . s ; extra block computes beta = b2 . s ----
__global__ __launch_bounds__(256) void k_gemv_row(const float* __restrict__ W,
                                                  const float* __restrict__ vin,
                                                  const float* __restrict__ b2,
                                                  float* __restrict__ vout,
                                                  float* __restrict__ beta) {
  __shared__ float red[4];
  if (blockIdx.x == HID / 4) {           // beta block
    float p = 0.f;
    for (int j = threadIdx.x; j < HID; j += 256) p += b2[j] * vin[j];
    #pragma unroll
    for (int o = 32; o > 0; o >>= 1) p += __shfl_down(p, o);
    int lane = threadIdx.x & 63, w = threadIdx.x >> 6;
    if (lane == 0) red[w] = p;
    __syncthreads();
    if (threadIdx.x == 0) beta[0] = red[0] + red[1] + red[2] + red[3];
    return;
  }
  int w = threadIdx.x >> 6, lane = threadIdx.x & 63;
  int row = blockIdx.x * 4 + w;
  const float* base = W + (size_t)row * HID;
  float p = 0.f;
  #pragma unroll 8
  for (int j = lane * 4; j < HID; j += 256) {
    float4 wv = *(const float4*)(base + j);
    float4 sv = *(const float4*)(vin + j);
    p += wv.x * sv.x + wv.y * sv.y + wv.z * sv.z + wv.w * sv.w;
  }
  #pragma unroll
  for (int o = 32; o > 0; o >>= 1) p += __shfl_down(p, o);
  if (lane == 0) vout[row] = p;
}

// ---- K4: kv[row] = A[row,:] . t + beta   (A bf16) ----
__global__ __launch_bounds__(256) void k_kv(const short* __restrict__ A,
                                            const float* __restrict__ t,
                                            const float* __restrict__ beta,
                                            float* __restrict__ kv) {
  int w = threadIdx.x >> 6, lane = threadIdx.x & 63;
  int row = blockIdx.x * 4 + w;
  const short* base = A + (size_t)row * HID;
  float p = 0.f;
  #pragma unroll
  for (int j = lane * 8; j < HID; j += 512) {
    bf16x8 av = *(const bf16x8*)(base + j);
    float4 t0 = *(const float4*)(t + j);
    float4 t1 = *(const float4*)(t + j + 4);
    p += b2f(av[0]) * t0.x + b2f(av[1]) * t0.y + b2f(av[2]) * t0.z + b2f(av[3]) * t0.w
       + b2f(av[4]) * t1.x + b2f(av[5]) * t1.y + b2f(av[6]) * t1.z + b2f(av[7]) * t1.w;
  }
  #pragma unroll
  for (int o = 32; o > 0; o >>= 1) p += __shfl_down(p, o);
  if (lane == 0) kv[row] = p + beta[0];
}

// ---- K6: out = relu(uacc) . W4 + b4 ----
__global__ __launch_bounds__(256) void k_final(const float* __restrict__ uacc,
                                               const float* __restrict__ W4,
                                               const float* __restrict__ b4,
                                               float* __restrict__ out) {
  __shared__ float red[4];
  float p = 0.f;
  for (int j = threadIdx.x; j < HID; j += 256) {
    float uv = uacc[j];
    uv = uv > 0.f ? uv : 0.f;
    p += uv * W4[j];
  }
  #pragma unroll
  for (int o = 32; o > 0; o >>= 1) p += __shfl_down(p, o);
  int lane = threadIdx.x & 63, w = threadIdx.x >> 6;
  if (lane == 0) red[w] = p;
  __syncthreads();
  if (threadIdx.x == 0) out[0] = red[0] + red[1] + red[2] + red[3] + b4[0];
}

extern "C" void kernel_launch(void* const* d_in, const int* in_sizes, int n_in,
                              void* d_out, int out_size, void* d_ws, size_t ws_size,
                              hipStream_t stream) {
  const float* x  = (const float*)d_in[0];
  // d_in[1] = edge_index (dead in the reference)
  const float* W1 = (const float*)d_in[2];
  const float* b1 = (const float*)d_in[3];
  const float* W2 = (const float*)d_in[4];
  const float* b2 = (const float*)d_in[5];
  const float* W3 = (const float*)d_in[6];
  const float* b3 = (const float*)d_in[7];
  const float* W4 = (const float*)d_in[8];
  const float* b4 = (const float*)d_in[9];
  float* out = (float*)d_out;

  char* ws = (char*)d_ws;
  short* Abf  = (short*)(ws);                 // 32 MB
  short* xb   = (short*)(ws + 33554432);      // 4 MB
  short* w1t  = (short*)(ws + 37748736);      // 4 MB
  float* aacc = (float*)(ws + 41943040);
  float* svec = (float*)(ws + 41959424);
  float* tvec = (float*)(ws + 41975808);
  float* kvv  = (float*)(ws + 41992192);
  float* uacc = (float*)(ws + 42008576);
  float* beta = (float*)(ws + 42024960);

  k_prep    <<<dim3(4112),     dim3(256), 0, stream>>>(x, W1, b2, b3, xb, w1t, aacc, svec, uacc);
  k_gemm1   <<<dim3(256),      dim3(512), 0, stream>>>(xb, w1t, b1, Abf, aacc);
  k_gemv_at <<<dim3(4, 64),    dim3(256), 0, stream>>>(W2, aacc, svec);
  k_gemv_row<<<dim3(1025),     dim3(256), 0, stream>>>(W2, svec, b2, tvec, beta);
  k_kv      <<<dim3(1024),     dim3(256), 0, stream>>>(Abf, tvec, beta, kvv);
  k_gemv_at <<<dim3(4, 64),    dim3(256), 0, stream>>>(W3, kvv, uacc);
  k_final   <<<dim3(1),        dim3(256), 0, stream>>>(uacc, W4, b4, out);
}

// Round 10
// 96.317 us; speedup vs baseline: 1.0846x; 1.0137x over previous
//
#include <hip/hip_runtime.h>

#define NODES 4096
#define NDIM  512
#define HID   4096

typedef __attribute__((ext_vector_type(8))) short bf16x8;
typedef __attribute__((ext_vector_type(4))) float f32x4;

__device__ __forceinline__ float b2f(short v) {
  union { unsigned int u; float f; } c;
  c.u = ((unsigned int)(unsigned short)v) << 16;
  return c.f;
}
__device__ __forceinline__ short f2b(float f) {
  union { float f; unsigned int u; } c; c.f = f;
  unsigned int r = c.u + 0x7fffu + ((c.u >> 16) & 1u);  // round-nearest-even
  return (short)(r >> 16);
}

// ---- K0: fused prep: cast x->bf16 | transpose+cast W1 | init accumulators ----
__global__ __launch_bounds__(256) void k_prep(const float* __restrict__ x,
                                              const float* __restrict__ W1,
                                              const float* __restrict__ b2,
                                              const float* __restrict__ b3,
                                              short* __restrict__ xb,
                                              short* __restrict__ w1t,
                                              float* __restrict__ aacc,
                                              float* __restrict__ svec,
                                              float* __restrict__ uacc) {
  __shared__ float tile[32][33];
  int b = blockIdx.x;
  if (b < 2048) {                       // cast x (4096x512 fp32 -> bf16)
    int i = (b * 256 + threadIdx.x) * 4;
    float4 v = *(const float4*)(x + i);
    short4 o;
    o.x = f2b(v.x); o.y = f2b(v.y); o.z = f2b(v.z); o.w = f2b(v.w);
    *(short4*)(xb + i) = o;
  } else if (b < 4096) {                // transpose W1 [512][4096] -> [4096][512] bf16
    int t = b - 2048;
    int n0 = (t & 127) * 32;
    int k0 = (t >> 7) * 32;
    int tx = threadIdx.x & 31, ty = threadIdx.x >> 5;
    #pragma unroll
    for (int j = 0; j < 4; ++j) {
      int kk = ty + j * 8;
      tile[kk][tx] = W1[(size_t)(k0 + kk) * HID + n0 + tx];
    }
    __syncthreads();
    #pragma unroll
    for (int j = 0; j < 4; ++j) {
      int nn = ty + j * 8;
      w1t[(size_t)(n0 + nn) * NDIM + k0 + tx] = f2b(tile[tx][nn]);
    }
  } else {                              // init: a=0, s=N*b2, u=b3
    int j = (b - 4096) * 256 + threadIdx.x;
    aacc[j] = 0.0f;
    svec[j] = (float)NODES * b2[j];
    uacc[j] = b3[j];
  }
}

// ---- K1: A = relu(x @ W1 + b1) (bf16 MFMA), fused column sums ----
// 256x256 tile, BK=64 as two [256][32] subtiles (64-B rows, proven layout),
// dbuf dynamic LDS (128 KB), counted vmcnt(8), setprio around MFMA.
// 8 waves (2M x 4N). Swapped-operand MFMA -> C^T frags -> packed short4 stores.
__global__ __launch_bounds__(512, 2) void k_gemm1(const short* __restrict__ xb,
                                                  const short* __restrict__ w1t,
                                                  const float* __restrict__ b1,
                                                  short* __restrict__ Aout,
                                                  float* __restrict__ colsum) {
  extern __shared__ char smem[];        // 131072 B:
                                        // A: buf*32768 + kh*16384   (0..65535)
                                        // B: 65536 + buf*32768 + kh*16384
  __shared__ float csum[256];

  const int tid  = threadIdx.x;
  const int lane = tid & 63;
  const int wid  = tid >> 6;            // 0..7
  const int wr   = wid >> 2;            // 0..1  (M)
  const int wc   = wid & 3;             // 0..3  (N)

  // XCD-aware swizzle (256 blocks, %8==0 -> simple bijective form)
  int bswz = (blockIdx.x & 7) * 32 + (blockIdx.x >> 3);
  const int brow = (bswz >> 4) * 256, bcol = (bswz & 15) * 256;

  f32x4 acc[8][4];
  #pragma unroll
  for (int i = 0; i < 8; ++i)
    #pragma unroll
    for (int j = 0; j < 4; ++j)
      acc[i][j] = (f32x4){0.f, 0.f, 0.f, 0.f};

  if (tid < 256) csum[tid] = 0.f;

  const int fr = lane & 15;
  const int fk = (lane >> 4) * 8;       // 8 consecutive k per lane (shorts)

  // staging: each subtile is [256][32] shorts, 64-B rows, LDS linear.
  // Thread covers 16 B at off0 (rows 0..127) and off0+8192 (rows 128..255).
  const int off0 = tid * 16;
  const int row0 = off0 >> 6, ce0 = (off0 & 63) >> 1;   // ce0 in [0,32)
  const short* gA0 = xb  + (size_t)(brow + row0) * NDIM + ce0;
  const short* gA1 = xb  + (size_t)(brow + row0 + 128) * NDIM + ce0;
  const short* gB0 = w1t + (size_t)(bcol + row0) * NDIM + ce0;
  const short* gB1 = w1t + (size_t)(bcol + row0 + 128) * NDIM + ce0;

  // Exactly 8 global_load_lds per wave per call (one 64-wide K-tile).
  auto STAGE = [&](int buf, int kt2) {
    char* baseA = smem + buf * 32768;
    char* baseB = smem + 65536 + buf * 32768;
    const int ks = kt2 * 64;
    #pragma unroll
    for (int kh = 0; kh < 2; ++kh) {
      __builtin_amdgcn_global_load_lds(
          (const __attribute__((address_space(1))) void*)(gA0 + ks + kh * 32),
          (__attribute__((address_space(3))) void*)(baseA + kh * 16384 + off0), 16, 0, 0);
      __builtin_amdgcn_global_load_lds(
          (const __attribute__((address_space(1))) void*)(gA1 + ks + kh * 32),
          (__attribute__((address_space(3))) void*)(baseA + kh * 16384 + off0 + 8192), 16, 0, 0);
      __builtin_amdgcn_global_load_lds(
          (const __attribute__((address_space(1))) void*)(gB0 + ks + kh * 32),
          (__attribute__((address_space(3))) void*)(baseB + kh * 16384 + off0), 16, 0, 0);
      __builtin_amdgcn_global_load_lds(
          (const __attribute__((address_space(1))) void*)(gB1 + ks + kh * 32),
          (__attribute__((address_space(3))) void*)(baseB + kh * 16384 + off0 + 8192), 16, 0, 0);
    }
  };

  auto COMPUTE = [&](int buf) {
    #pragma unroll
    for (int kh = 0; kh < 2; ++kh) {
      bf16x8 af[8], bfr[4];
      const short* Ab = (const short*)(smem + buf * 32768 + kh * 16384);
      const short* Bb = (const short*)(smem + 65536 + buf * 32768 + kh * 16384);
      #pragma unroll
      for (int ni = 0; ni < 4; ++ni)
        bfr[ni] = *(const bf16x8*)(Bb + (wc * 64 + ni * 16 + fr) * 32 + fk);
      #pragma unroll
      for (int mi = 0; mi < 8; ++mi)
        af[mi] = *(const bf16x8*)(Ab + (wr * 128 + mi * 16 + fr) * 32 + fk);
      // swapped operands: acc[mi][ni] = C^T fragment
      // value(lane,reg) = C[row = mi*16+(lane&15)][col = ni*16+(lane>>4)*4+reg]
      __builtin_amdgcn_s_setprio(1);
      #pragma unroll
      for (int mi = 0; mi < 8; ++mi)
        #pragma unroll
        for (int ni = 0; ni < 4; ++ni)
          acc[mi][ni] = __builtin_amdgcn_mfma_f32_16x16x32_bf16(bfr[ni], af[mi],
                                                                acc[mi][ni], 0, 0, 0);
      __builtin_amdgcn_s_setprio(0);
    }
  };

  STAGE(0, 0);                                     // 8 VMEM in flight (tile 0)
  #pragma unroll 1
  for (int kt2 = 0; kt2 < NDIM / 64 - 1; ++kt2) {  // kt2 = 0..6
    STAGE((kt2 + 1) & 1, kt2 + 1);                 // +8 VMEM (tile kt2+1)
    asm volatile("s_waitcnt vmcnt(8)" ::: "memory");  // tile kt2 landed; +1 in flight
    __builtin_amdgcn_s_barrier();                  // all waves: tile kt2 visible
    COMPUTE(kt2 & 1);
    __builtin_amdgcn_s_barrier();                  // all done reading buf kt2&1
  }
  asm volatile("s_waitcnt vmcnt(0)" ::: "memory"); // last tile landed
  __builtin_amdgcn_s_barrier();
  COMPUTE((NDIM / 64 - 1) & 1);

  // epilogue: bias + relu + packed short4 stores + shuffle-reduced column sums
  const int cr = lane & 15;            // output row within 16-frag
  const int cg = (lane >> 4) * 4;      // output col base within 16-frag
  float4 bias4[4];
  #pragma unroll
  for (int ni = 0; ni < 4; ++ni)
    bias4[ni] = *(const float4*)(b1 + bcol + wc * 64 + ni * 16 + cg);

  float cl[4][4];
  #pragma unroll
  for (int ni = 0; ni < 4; ++ni)
    #pragma unroll
    for (int r = 0; r < 4; ++r)
      cl[ni][r] = 0.f;

  #pragma unroll
  for (int mi = 0; mi < 8; ++mi) {
    int grow = brow + wr * 128 + mi * 16 + cr;
    short* orow = Aout + (size_t)grow * HID + bcol + wc * 64;
    #pragma unroll
    for (int ni = 0; ni < 4; ++ni) {
      float v0 = fmaxf(acc[mi][ni][0] + bias4[ni].x, 0.f);
      float v1 = fmaxf(acc[mi][ni][1] + bias4[ni].y, 0.f);
      float v2 = fmaxf(acc[mi][ni][2] + bias4[ni].z, 0.f);
      float v3 = fmaxf(acc[mi][ni][3] + bias4[ni].w, 0.f);
      cl[ni][0] += v0; cl[ni][1] += v1; cl[ni][2] += v2; cl[ni][3] += v3;
      short4 o;
      o.x = f2b(v0); o.y = f2b(v1); o.z = f2b(v2); o.w = f2b(v3);
      *(short4*)(orow + ni * 16 + cg) = o;
    }
  }
  // sum over the 16 rows (lanes sharing lane>>4) via xor-butterfly on low 4 bits
  #pragma unroll
  for (int ni = 0; ni < 4; ++ni)
    #pragma unroll
    for (int r = 0; r < 4; ++r) {
      #pragma unroll
      for (int m = 1; m < 16; m <<= 1)
        cl[ni][r] += __shfl_xor(cl[ni][r], m);
    }
  if (cr == 0) {                       // 4 lanes/wave; wr=0/1 -> 2-way contention
    #pragma unroll
    for (int ni = 0; ni < 4; ++ni)
      #pragma unroll
      for (int r = 0; r < 4; ++r)
        atomicAdd(&csum[wc * 64 + ni * 16 + cg + r], cl[ni][r]);
  }
  __syncthreads();
  if (tid < 256) atomicAdd(&colsum[bcol + tid], csum[tid]);
}

// ---- K2/K5: vout[col] += sum_i vin[i] * W[i][col]  (W: [4096][4096] fp32) ----
__global__ __launch_bounds__(256) void k_gemv_at(const float* __restrict__ W,
                                                 const float* __restrict__ vin,
                                                 float* __restrict__ vout) {
  const int col = blockIdx.x * 1024 + threadIdx.x * 4;
  const int r0  = blockIdx.y * 64;
  float4 accv = {0.f, 0.f, 0.f, 0.f};
  const float* base = W + (size_t)r0 * HID + col;
  #pragma unroll 16
  for (int i = 0; i < 64; ++i) {
    float vi = vin[r0 + i];
    float4 wv = *(const float4*)(base + (size_t)i * HID);
    accv.x += vi * wv.x; accv.y += vi * wv.y;
    accv.z += vi * wv.z; accv.w += vi * wv.w;
  }
  atomicAdd(&vout[col + 0], accv.x);
  atomicAdd(&vout[col + 1], accv.y);
  atomicAdd(&vout[col + 2], accv.z);
  atomicAdd(&vout[col + 3], accv.w);
}

// ---- K3: t[row] = W2[row,:] . s ; extra block computes beta = b2 . s ----
__global__ __launch_bounds__(256) void k_gemv_row(const float* __restrict__ W,
                                                  const float* __restrict__ vin,
                                                  const float* __restrict__ b2,
                                                  float* __restrict__ vout,
                                                  float* __restrict__ beta) {
  __shared__ float red[4];
  if (blockIdx.x == HID / 4) {           // beta block
    float p = 0.f;
    for (int j = threadIdx.x; j < HID; j += 256) p += b2[j] * vin[j];
    #pragma unroll
    for (int o = 32; o > 0; o >>= 1) p += __shfl_down(p, o);
    int lane = threadIdx.x & 63, w = threadIdx.x >> 6;
    if (lane == 0) red[w] = p;
    __syncthreads();
    if (threadIdx.x == 0) beta[0] = red[0] + red[1] + red[2] + red[3];
    return;
  }
  int w = threadIdx.x >> 6, lane = threadIdx.x & 63;
  int row = blockIdx.x * 4 + w;
  const float* base = W + (size_t)row * HID;
  float p = 0.f;
  #pragma unroll 8
  for (int j = lane * 4; j < HID; j += 256) {
    float4 wv = *(const float4*)(base + j);
    float4 sv = *(const float4*)(vin + j);
    p += wv.x * sv.x + wv.y * sv.y + wv.z * sv.z + wv.w * sv.w;
  }
  #pragma unroll
  for (int o = 32; o > 0; o >>= 1) p += __shfl_down(p, o);
  if (lane == 0) vout[row] = p;
}

// ---- K4: kv[row] = A[row,:] . t + beta   (A bf16) ----
__global__ __launch_bounds__(256) void k_kv(const short* __restrict__ A,
                                            const float* __restrict__ t,
                                            const float* __restrict__ beta,
                                            float* __restrict__ kv) {
  int w = threadIdx.x >> 6, lane = threadIdx.x & 63;
  int row = blockIdx.x * 4 + w;
  const short* base = A + (size_t)row * HID;
  float p = 0.f;
  #pragma unroll
  for (int j = lane * 8; j < HID; j += 512) {
    bf16x8 av = *(const bf16x8*)(base + j);
    float4 t0 = *(const float4*)(t + j);
    float4 t1 = *(const float4*)(t + j + 4);
    p += b2f(av[0]) * t0.x + b2f(av[1]) * t0.y + b2f(av[2]) * t0.z + b2f(av[3]) * t0.w
       + b2f(av[4]) * t1.x + b2f(av[5]) * t1.y + b2f(av[6]) * t1.z + b2f(av[7]) * t1.w;
  }
  #pragma unroll
  for (int o = 32; o > 0; o >>= 1) p += __shfl_down(p, o);
  if (lane == 0) kv[row] = p + beta[0];
}

// ---- K6: out = relu(uacc) . W4 + b4 ----
__global__ __launch_bounds__(256) void k_final(const float* __restrict__ uacc,
                                               const float* __restrict__ W4,
                                               const float* __restrict__ b4,
                                               float* __restrict__ out) {
  __shared__ float red[4];
  float p = 0.f;
  for (int j = threadIdx.x; j < HID; j += 256) {
    float uv = uacc[j];
    uv = uv > 0.f ? uv : 0.f;
    p += uv * W4[j];
  }
  #pragma unroll
  for (int o = 32; o > 0; o >>= 1) p += __shfl_down(p, o);
  int lane = threadIdx.x & 63, w = threadIdx.x >> 6;
  if (lane == 0) red[w] = p;
  __syncthreads();
  if (threadIdx.x == 0) out[0] = red[0] + red[1] + red[2] + red[3] + b4[0];
}

extern "C" void kernel_launch(void* const* d_in, const int* in_sizes, int n_in,
                              void* d_out, int out_size, void* d_ws, size_t ws_size,
                              hipStream_t stream) {
  const float* x  = (const float*)d_in[0];
  // d_in[1] = edge_index (dead in the reference)
  const float* W1 = (const float*)d_in[2];
  const float* b1 = (const float*)d_in[3];
  const float* W2 = (const float*)d_in[4];
  const float* b2 = (const float*)d_in[5];
  const float* W3 = (const float*)d_in[6];
  const float* b3 = (const float*)d_in[7];
  const float* W4 = (const float*)d_in[8];
  const float* b4 = (const float*)d_in[9];
  float* out = (float*)d_out;

  char* ws = (char*)d_ws;
  short* Abf  = (short*)(ws);                 // 32 MB
  short* xb   = (short*)(ws + 33554432);      // 4 MB
  short* w1t  = (short*)(ws + 37748736);      // 4 MB
  float* aacc = (float*)(ws + 41943040);
  float* svec = (float*)(ws + 41959424);
  float* tvec = (float*)(ws + 41975808);
  float* kvv  = (float*)(ws + 41992192);
  float* uacc = (float*)(ws + 42008576);
  float* beta = (float*)(ws + 42024960);

  k_prep    <<<dim3(4112),     dim3(256), 0, stream>>>(x, W1, b2, b3, xb, w1t, aacc, svec, uacc);
  k_gemm1   <<<dim3(256),      dim3(512), 131072, stream>>>(xb, w1t, b1, Abf, aacc);
  k_gemv_at <<<dim3(4, 64),    dim3(256), 0, stream>>>(W2, aacc, svec);
  k_gemv_row<<<dim3(1025),     dim3(256), 0, stream>>>(W2, svec, b2, tvec, beta);
  k_kv      <<<dim3(1024),     dim3(256), 0, stream>>>(Abf, tvec, beta, kvv);
  k_gemv_at <<<dim3(4, 64),    dim3(256), 0, stream>>>(W3, kvv, uacc);
  k_final   <<<dim3(1),        dim3(256), 0, stream>>>(uacc, W4, b4, out);
}

// Round 11
// 95.086 us; speedup vs baseline: 1.0986x; 1.0129x over previous
//
#include <hip/hip_runtime.h>

#define NODES 4096
#define NDIM  512
#define HID   4096

typedef __attribute__((ext_vector_type(8))) short bf16x8;
typedef __attribute__((ext_vector_type(4))) float f32x4;

__device__ __forceinline__ float b2f(short v) {
  union { unsigned int u; float f; } c;
  c.u = ((unsigned int)(unsigned short)v) << 16;
  return c.f;
}
__device__ __forceinline__ short f2b(float f) {
  union { float f; unsigned int u; } c; c.f = f;
  unsigned int r = c.u + 0x7fffu + ((c.u >> 16) & 1u);  // round-nearest-even
  return (short)(r >> 16);
}

// ---- K0: fused prep: cast x->bf16 | transpose+cast W1 | init accumulators ----
__global__ __launch_bounds__(256) void k_prep(const float* __restrict__ x,
                                              const float* __restrict__ W1,
                                              const float* __restrict__ b2,
                                              const float* __restrict__ b3,
                                              short* __restrict__ xb,
                                              short* __restrict__ w1t,
                                              float* __restrict__ aacc,
                                              float* __restrict__ svec,
                                              float* __restrict__ uacc) {
  __shared__ float tile[32][33];
  int b = blockIdx.x;
  if (b < 2048) {                       // cast x (4096x512 fp32 -> bf16)
    int i = (b * 256 + threadIdx.x) * 4;
    float4 v = *(const float4*)(x + i);
    short4 o;
    o.x = f2b(v.x); o.y = f2b(v.y); o.z = f2b(v.z); o.w = f2b(v.w);
    *(short4*)(xb + i) = o;
  } else if (b < 4096) {                // transpose W1 [512][4096] -> [4096][512] bf16
    int t = b - 2048;
    int n0 = (t & 127) * 32;
    int k0 = (t >> 7) * 32;
    int tx = threadIdx.x & 31, ty = threadIdx.x >> 5;
    #pragma unroll
    for (int j = 0; j < 4; ++j) {
      int kk = ty + j * 8;
      tile[kk][tx] = W1[(size_t)(k0 + kk) * HID + n0 + tx];
    }
    __syncthreads();
    #pragma unroll
    for (int j = 0; j < 4; ++j) {
      int nn = ty + j * 8;
      w1t[(size_t)(n0 + nn) * NDIM + k0 + tx] = f2b(tile[tx][nn]);
    }
  } else {                              // init: a=0, s=N*b2, u=b3
    int j = (b - 4096) * 256 + threadIdx.x;
    aacc[j] = 0.0f;
    svec[j] = (float)NODES * b2[j];
    uacc[j] = b3[j];
  }
}

// ---- K1: A = relu(x @ W1 + b1) (bf16 MFMA), fused column sums ----
// 256x256 tile, BK=64 (two [256][32] subtiles), dbuf dynamic LDS (128 KB),
// counted vmcnt(8), setprio. Granule XOR swizzle g^=(row>>1)&3 (within 64-B
// rows, both-sides involution). Epilogue: padded-LDS repack -> coalesced
// b128 stores (two 128-row halves).
__global__ __launch_bounds__(512, 2) void k_gemm1(const short* __restrict__ xb,
                                                  const short* __restrict__ w1t,
                                                  const float* __restrict__ b1,
                                                  short* __restrict__ Aout,
                                                  float* __restrict__ colsum) {
  extern __shared__ char smem[];        // 131072 B:
                                        // A: buf*32768 + kh*16384   (0..65535)
                                        // B: 65536 + buf*32768 + kh*16384
  __shared__ float csum[256];

  const int tid  = threadIdx.x;
  const int lane = tid & 63;
  const int wid  = tid >> 6;            // 0..7
  const int wr   = wid >> 2;            // 0..1  (M)
  const int wc   = wid & 3;             // 0..3  (N)

  // XCD-aware swizzle (256 blocks, %8==0 -> simple bijective form)
  int bswz = (blockIdx.x & 7) * 32 + (blockIdx.x >> 3);
  const int brow = (bswz >> 4) * 256, bcol = (bswz & 15) * 256;

  f32x4 acc[8][4];
  #pragma unroll
  for (int i = 0; i < 8; ++i)
    #pragma unroll
    for (int j = 0; j < 4; ++j)
      acc[i][j] = (f32x4){0.f, 0.f, 0.f, 0.f};

  if (tid < 256) csum[tid] = 0.f;

  const int fr = lane & 15;
  // swizzled fragment granule: logical g = lane>>4, row-phase = (fr>>1)&3
  const int fko = ((lane >> 4) ^ ((lane >> 1) & 3)) * 8;  // shorts, in [0,32)

  // staging: each subtile is [256][32] shorts (64-B rows), LDS dest linear.
  // Source granule pre-swizzled with the SAME involution: g' = g ^ ((row>>1)&3).
  const int off0 = tid * 16;
  const int row0 = off0 >> 6;
  const int gs   = (off0 >> 4) & 3;                     // linear granule
  const int ce0  = (gs ^ ((row0 >> 1) & 3)) * 8;        // swizzled source offset
  const short* gA0 = xb  + (size_t)(brow + row0) * NDIM + ce0;
  const short* gA1 = xb  + (size_t)(brow + row0 + 128) * NDIM + ce0;   // (row0+128)>>1 &3 same
  const short* gB0 = w1t + (size_t)(bcol + row0) * NDIM + ce0;
  const short* gB1 = w1t + (size_t)(bcol + row0 + 128) * NDIM + ce0;

  // Exactly 8 global_load_lds per wave per call (one 64-wide K-tile).
  auto STAGE = [&](int buf, int kt2) {
    char* baseA = smem + buf * 32768;
    char* baseB = smem + 65536 + buf * 32768;
    const int ks = kt2 * 64;
    #pragma unroll
    for (int kh = 0; kh < 2; ++kh) {
      __builtin_amdgcn_global_load_lds(
          (const __attribute__((address_space(1))) void*)(gA0 + ks + kh * 32),
          (__attribute__((address_space(3))) void*)(baseA + kh * 16384 + off0), 16, 0, 0);
      __builtin_amdgcn_global_load_lds(
          (const __attribute__((address_space(1))) void*)(gA1 + ks + kh * 32),
          (__attribute__((address_space(3))) void*)(baseA + kh * 16384 + off0 + 8192), 16, 0, 0);
      __builtin_amdgcn_global_load_lds(
          (const __attribute__((address_space(1))) void*)(gB0 + ks + kh * 32),
          (__attribute__((address_space(3))) void*)(baseB + kh * 16384 + off0), 16, 0, 0);
      __builtin_amdgcn_global_load_lds(
          (const __attribute__((address_space(1))) void*)(gB1 + ks + kh * 32),
          (__attribute__((address_space(3))) void*)(baseB + kh * 16384 + off0 + 8192), 16, 0, 0);
    }
  };

  auto COMPUTE = [&](int buf) {
    #pragma unroll
    for (int kh = 0; kh < 2; ++kh) {
      bf16x8 af[8], bfr[4];
      const short* Ab = (const short*)(smem + buf * 32768 + kh * 16384);
      const short* Bb = (const short*)(smem + 65536 + buf * 32768 + kh * 16384);
      #pragma unroll
      for (int ni = 0; ni < 4; ++ni)
        bfr[ni] = *(const bf16x8*)(Bb + (wc * 64 + ni * 16 + fr) * 32 + fko);
      #pragma unroll
      for (int mi = 0; mi < 8; ++mi)
        af[mi] = *(const bf16x8*)(Ab + (wr * 128 + mi * 16 + fr) * 32 + fko);
      // swapped operands: acc[mi][ni] = C^T fragment
      // value(lane,reg) = C[row = mi*16+(lane&15)][col = ni*16+(lane>>4)*4+reg]
      __builtin_amdgcn_s_setprio(1);
      #pragma unroll
      for (int mi = 0; mi < 8; ++mi)
        #pragma unroll
        for (int ni = 0; ni < 4; ++ni)
          acc[mi][ni] = __builtin_amdgcn_mfma_f32_16x16x32_bf16(bfr[ni], af[mi],
                                                                acc[mi][ni], 0, 0, 0);
      __builtin_amdgcn_s_setprio(0);
    }
  };

  STAGE(0, 0);                                     // 8 VMEM in flight (tile 0)
  #pragma unroll 1
  for (int kt2 = 0; kt2 < NDIM / 64 - 1; ++kt2) {  // kt2 = 0..6
    STAGE((kt2 + 1) & 1, kt2 + 1);                 // +8 VMEM (tile kt2+1)
    asm volatile("s_waitcnt vmcnt(8)" ::: "memory");  // tile kt2 landed; +1 in flight
    __builtin_amdgcn_s_barrier();                  // all waves: tile kt2 visible
    COMPUTE(kt2 & 1);
    __builtin_amdgcn_s_barrier();                  // all done reading buf kt2&1
  }
  asm volatile("s_waitcnt vmcnt(0)" ::: "memory"); // last tile landed
  __builtin_amdgcn_s_barrier();
  COMPUTE((NDIM / 64 - 1) & 1);

  // ---- epilogue: bias + relu + csum; padded-LDS repack -> coalesced stores
  const int cr = lane & 15;            // output row within 16-frag
  const int cg = (lane >> 4) * 4;      // output col base within 16-frag
  float4 bias4[4];
  #pragma unroll
  for (int ni = 0; ni < 4; ++ni)
    bias4[ni] = *(const float4*)(b1 + bcol + wc * 64 + ni * 16 + cg);

  float cl[4][4];
  #pragma unroll
  for (int ni = 0; ni < 4; ++ni)
    #pragma unroll
    for (int r = 0; r < 4; ++r)
      cl[ni][r] = 0.f;

  short* pk = (short*)smem;            // [128][264] shorts = 67584 B (fits 128 KB)
  #pragma unroll 1
  for (int half = 0; half < 2; ++half) {
    __syncthreads();                   // K-loop reads / prev half's stores done
    if (wr == half) {                  // owning waves write their 128 rows
      #pragma unroll
      for (int mi = 0; mi < 8; ++mi) {
        int lrow = mi * 16 + cr;       // 0..127 within half
        #pragma unroll
        for (int ni = 0; ni < 4; ++ni) {
          float v0 = fmaxf(acc[mi][ni][0] + bias4[ni].x, 0.f);
          float v1 = fmaxf(acc[mi][ni][1] + bias4[ni].y, 0.f);
          float v2 = fmaxf(acc[mi][ni][2] + bias4[ni].z, 0.f);
          float v3 = fmaxf(acc[mi][ni][3] + bias4[ni].w, 0.f);
          cl[ni][0] += v0; cl[ni][1] += v1; cl[ni][2] += v2; cl[ni][3] += v3;
          short4 o;
          o.x = f2b(v0); o.y = f2b(v1); o.z = f2b(v2); o.w = f2b(v3);
          *(short4*)(pk + lrow * 264 + wc * 64 + ni * 16 + cg) = o;
        }
      }
    }
    __syncthreads();
    // all 8 waves store 64 KB: 128 rows x 512 B, fully coalesced b128
    #pragma unroll
    for (int i = 0; i < 8; ++i) {
      int c = tid + i * 512;           // 0..4095 chunks of 16 B
      int row = c >> 5, ch = c & 31;
      bf16x8 vv = *(const bf16x8*)(pk + row * 264 + ch * 8);
      *(bf16x8*)(Aout + (size_t)(brow + half * 128 + row) * HID + bcol + ch * 8) = vv;
    }
  }

  // column sums: reduce over the 16 rows (lanes sharing lane>>4)
  #pragma unroll
  for (int ni = 0; ni < 4; ++ni)
    #pragma unroll
    for (int r = 0; r < 4; ++r) {
      #pragma unroll
      for (int m = 1; m < 16; m <<= 1)
        cl[ni][r] += __shfl_xor(cl[ni][r], m);
    }
  if (cr == 0) {                       // 4 lanes/wave; wr=0/1 -> 2-way contention
    #pragma unroll
    for (int ni = 0; ni < 4; ++ni)
      #pragma unroll
      for (int r = 0; r < 4; ++r)
        atomicAdd(&csum[wc * 64 + ni * 16 + cg + r], cl[ni][r]);
  }
  __syncthreads();
  if (tid < 256) atomicAdd(&colsum[bcol + tid], csum[tid]);
}

// ---- K2/K5: vout[col] += sum_i vin[i] * W[i][col]  (W: [4096][4096] fp32) ----
__global__ __launch_bounds__(256) void k_gemv_at(const float* __restrict__ W,
                                                 const float* __restrict__ vin,
                                                 float* __restrict__ vout) {
  const int col = blockIdx.x * 1024 + threadIdx.x * 4;
  const int r0  = blockIdx.y * 64;
  float4 accv = {0.f, 0.f, 0.f, 0.f};
  const float* base = W + (size_t)r0 * HID + col;
  #pragma unroll 16
  for (int i = 0; i < 64; ++i) {
    float vi = vin[r0 + i];
    float4 wv = *(const float4*)(base + (size_t)i * HID);
    accv.x += vi * wv.x; accv.y += vi * wv.y;
    accv.z += vi * wv.z; accv.w += vi * wv.w;
  }
  atomicAdd(&vout[col + 0], accv.x);
  atomicAdd(&vout[col + 1], accv.y);
  atomicAdd(&vout[col + 2], accv.z);
  atomicAdd(&vout[col + 3], accv.w);
}

// ---- K3: t[row] = W2[row,:] . s ; extra block computes beta = b2 . s ----
__global__ __launch_bounds__(256) void k_gemv_row(const float* __restrict__ W,
                                                  const float* __restrict__ vin,
                                                  const float* __restrict__ b2,
                                                  float* __restrict__ vout,
                                                  float* __restrict__ beta) {
  __shared__ float red[4];
  if (blockIdx.x == HID / 4) {           // beta block
    float p = 0.f;
    for (int j = threadIdx.x; j < HID; j += 256) p += b2[j] * vin[j];
    #pragma unroll
    for (int o = 32; o > 0; o >>= 1) p += __shfl_down(p, o);
    int lane = threadIdx.x & 63, w = threadIdx.x >> 6;
    if (lane == 0) red[w] = p;
    __syncthreads();
    if (threadIdx.x == 0) beta[0] = red[0] + red[1] + red[2] + red[3];
    return;
  }
  int w = threadIdx.x >> 6, lane = threadIdx.x & 63;
  int row = blockIdx.x * 4 + w;
  const float* base = W + (size_t)row * HID;
  float p = 0.f;
  #pragma unroll 8
  for (int j = lane * 4; j < HID; j += 256) {
    float4 wv = *(const float4*)(base + j);
    float4 sv = *(const float4*)(vin + j);
    p += wv.x * sv.x + wv.y * sv.y + wv.z * sv.z + wv.w * sv.w;
  }
  #pragma unroll
  for (int o = 32; o > 0; o >>= 1) p += __shfl_down(p, o);
  if (lane == 0) vout[row] = p;
}

// ---- K4: kv[row] = A[row,:] . t + beta   (A bf16) ----
__global__ __launch_bounds__(256) void k_kv(const short* __restrict__ A,
                                            const float* __restrict__ t,
                                            const float* __restrict__ beta,
                                            float* __restrict__ kv) {
  int w = threadIdx.x >> 6, lane = threadIdx.x & 63;
  int row = blockIdx.x * 4 + w;
  const short* base = A + (size_t)row * HID;
  float p = 0.f;
  #pragma unroll
  for (int j = lane * 8; j < HID; j += 512) {
    bf16x8 av = *(const bf16x8*)(base + j);
    float4 t0 = *(const float4*)(t + j);
    float4 t1 = *(const float4*)(t + j + 4);
    p += b2f(av[0]) * t0.x + b2f(av[1]) * t0.y + b2f(av[2]) * t0.z + b2f(av[3]) * t0.w
       + b2f(av[4]) * t1.x + b2f(av[5]) * t1.y + b2f(av[6]) * t1.z + b2f(av[7]) * t1.w;
  }
  #pragma unroll
  for (int o = 32; o > 0; o >>= 1) p += __shfl_down(p, o);
  if (lane == 0) kv[row] = p + beta[0];
}

// ---- K6: out = relu(uacc) . W4 + b4 ----
__global__ __launch_bounds__(256) void k_final(const float* __restrict__ uacc,
                                               const float* __restrict__ W4,
                                               const float* __restrict__ b4,
                                               float* __restrict__ out) {
  __shared__ float red[4];
  float p = 0.f;
  for (int j = threadIdx.x; j < HID; j += 256) {
    float uv = uacc[j];
    uv = uv > 0.f ? uv : 0.f;
    p += uv * W4[j];
  }
  #pragma unroll
  for (int o = 32; o > 0; o >>= 1) p += __shfl_down(p, o);
  int lane = threadIdx.x & 63, w = threadIdx.x >> 6;
  if (lane == 0) red[w] = p;
  __syncthreads();
  if (threadIdx.x == 0) out[0] = red[0] + red[1] + red[2] + red[3] + b4[0];
}

extern "C" void kernel_launch(void* const* d_in, const int* in_sizes, int n_in,
                              void* d_out, int out_size, void* d_ws, size_t ws_size,
                              hipStream_t stream) {
  const float* x  = (const float*)d_in[0];
  // d_in[1] = edge_index (dead in the reference)
  const float* W1 = (const float*)d_in[2];
  const float* b1 = (const float*)d_in[3];
  const float* W2 = (const float*)d_in[4];
  const float* b2 = (const float*)d_in[5];
  const float* W3 = (const float*)d_in[6];
  const float* b3 = (const float*)d_in[7];
  const float* W4 = (const float*)d_in[8];
  const float* b4 = (const float*)d_in[9];
  float* out = (float*)d_out;

  char* ws = (char*)d_ws;
  short* Abf  = (short*)(ws);                 // 32 MB
  short* xb   = (short*)(ws + 33554432);      // 4 MB
  short* w1t  = (short*)(ws + 37748736);      // 4 MB
  float* aacc = (float*)(ws + 41943040);
  float* svec = (float*)(ws + 41959424);
  float* tvec = (float*)(ws + 41975808);
  float* kvv  = (float*)(ws + 41992192);
  float* uacc = (float*)(ws + 42008576);
  float* beta = (float*)(ws + 42024960);

  k_prep    <<<dim3(4112),     dim3(256), 0, stream>>>(x, W1, b2, b3, xb, w1t, aacc, svec, uacc);
  k_gemm1   <<<dim3(256),      dim3(512), 131072, stream>>>(xb, w1t, b1, Abf, aacc);
  k_gemv_at <<<dim3(4, 64),    dim3(256), 0, stream>>>(W2, aacc, svec);
  k_gemv_row<<<dim3(1025),     dim3(256), 0, stream>>>(W2, svec, b2, tvec, beta);
  k_kv      <<<dim3(1024),     dim3(256), 0, stream>>>(Abf, tvec, beta, kvv);
  k_gemv_at <<<dim3(4, 64),    dim3(256), 0, stream>>>(W3, kvv, uacc);
  k_final   <<<dim3(1),        dim3(256), 0, stream>>>(uacc, W4, b4, out);
}

// Round 12
// 92.859 us; speedup vs baseline: 1.1249x; 1.0240x over previous
//
#include <hip/hip_runtime.h>

#define NODES 4096
#define NDIM  512
#define HID   4096

typedef __attribute__((ext_vector_type(8))) short bf16x8;
typedef __attribute__((ext_vector_type(4))) float f32x4;

__device__ __forceinline__ float b2f(short v) {
  union { unsigned int u; float f; } c;
  c.u = ((unsigned int)(unsigned short)v) << 16;
  return c.f;
}
__device__ __forceinline__ short f2b(float f) {
  union { float f; unsigned int u; } c; c.f = f;
  unsigned int r = c.u + 0x7fffu + ((c.u >> 16) & 1u);  // round-nearest-even
  return (short)(r >> 16);
}

// ---- K0: fused prep: cast x->bf16 | transpose+cast W1 | init accumulators ----
__global__ __launch_bounds__(256) void k_prep(const float* __restrict__ x,
                                              const float* __restrict__ W1,
                                              const float* __restrict__ b2,
                                              const float* __restrict__ b3,
                                              short* __restrict__ xb,
                                              short* __restrict__ w1t,
                                              float* __restrict__ aacc,
                                              float* __restrict__ svec,
                                              float* __restrict__ uacc) {
  __shared__ float tile[32][33];
  int b = blockIdx.x;
  if (b < 2048) {                       // cast x (4096x512 fp32 -> bf16)
    int i = (b * 256 + threadIdx.x) * 4;
    float4 v = *(const float4*)(x + i);
    short4 o;
    o.x = f2b(v.x); o.y = f2b(v.y); o.z = f2b(v.z); o.w = f2b(v.w);
    *(short4*)(xb + i) = o;
  } else if (b < 4096) {                // transpose W1 [512][4096] -> [4096][512] bf16
    int t = b - 2048;
    int n0 = (t & 127) * 32;
    int k0 = (t >> 7) * 32;
    int tx = threadIdx.x & 31, ty = threadIdx.x >> 5;
    #pragma unroll
    for (int j = 0; j < 4; ++j) {
      int kk = ty + j * 8;
      tile[kk][tx] = W1[(size_t)(k0 + kk) * HID + n0 + tx];
    }
    __syncthreads();
    #pragma unroll
    for (int j = 0; j < 4; ++j) {
      int nn = ty + j * 8;
      w1t[(size_t)(n0 + nn) * NDIM + k0 + tx] = f2b(tile[tx][nn]);
    }
  } else {                              // init: a=0, s=N*b2, u=b3
    int j = (b - 4096) * 256 + threadIdx.x;
    aacc[j] = 0.0f;
    svec[j] = (float)NODES * b2[j];
    uacc[j] = b3[j];
  }
}

// ---- K1: A = relu(x @ W1 + b1) (bf16 MFMA), fused column sums ----
// 256x256 tile, BK=64, 8 waves (2M x 4N, 128x64/wave). 4-phase fine-interleave
// per K-tile (8-phase-template port): {ds_read || half-tile stage -> barrier ->
// lgkmcnt(0) -> 16 MFMA -> barrier}, counted vmcnt(8) one phase ahead of the
// consuming read. Granule swizzle + padded-LDS repack epilogue (proven R11).
__global__ __launch_bounds__(512, 2) void k_gemm1(const short* __restrict__ xb,
                                                  const short* __restrict__ w1t,
                                                  const float* __restrict__ b1,
                                                  short* __restrict__ Aout,
                                                  float* __restrict__ colsum) {
  extern __shared__ char smem[];        // 131072 B:
                                        // A: buf*32768 + kh*16384   (0..65535)
                                        // B: 65536 + buf*32768 + kh*16384
  __shared__ float csum[256];

  const int tid  = threadIdx.x;
  const int lane = tid & 63;
  const int wid  = tid >> 6;            // 0..7
  const int wr   = wid >> 2;            // 0..1  (M)
  const int wc   = wid & 3;             // 0..3  (N)

  // XCD-aware swizzle (256 blocks, %8==0 -> simple bijective form)
  int bswz = (blockIdx.x & 7) * 32 + (blockIdx.x >> 3);
  const int brow = (bswz >> 4) * 256, bcol = (bswz & 15) * 256;

  f32x4 acc[8][4];
  #pragma unroll
  for (int i = 0; i < 8; ++i)
    #pragma unroll
    for (int j = 0; j < 4; ++j)
      acc[i][j] = (f32x4){0.f, 0.f, 0.f, 0.f};

  if (tid < 256) csum[tid] = 0.f;

  const int fr = lane & 15;
  // swizzled fragment granule: logical g = lane>>4, row-phase = (fr>>1)&3
  const int fko = ((lane >> 4) ^ ((lane >> 1) & 3)) * 8;  // shorts, in [0,32)

  // staging: each kh-subtile is [256][32] shorts (64-B rows), LDS dest linear.
  // Source granule pre-swizzled with the SAME involution: g' = g ^ ((row>>1)&3).
  const int off0 = tid * 16;
  const int row0 = off0 >> 6;
  const int gs   = (off0 >> 4) & 3;                     // linear granule
  const int ce0  = (gs ^ ((row0 >> 1) & 3)) * 8;        // swizzled source offset
  const short* gA0 = xb  + (size_t)(brow + row0) * NDIM + ce0;
  const short* gA1 = xb  + (size_t)(brow + row0 + 128) * NDIM + ce0;
  const short* gB0 = w1t + (size_t)(bcol + row0) * NDIM + ce0;
  const short* gB1 = w1t + (size_t)(bcol + row0 + 128) * NDIM + ce0;

#define GLOAD(src, dst) __builtin_amdgcn_global_load_lds( \
    (const __attribute__((address_space(1))) void*)(src), \
    (__attribute__((address_space(3))) void*)(dst), 16, 0, 0)

  // 4 global_load_lds per call (one kh half-tile: A-half + B-half)
#define STAGE_HALF(buf, tile_, kh) do { \
    char* bA_ = smem + (buf) * 32768 + (kh) * 16384; \
    char* bB_ = smem + 65536 + (buf) * 32768 + (kh) * 16384; \
    int ks_ = (tile_) * 64 + (kh) * 32; \
    GLOAD(gA0 + ks_, bA_ + off0); \
    GLOAD(gA1 + ks_, bA_ + off0 + 8192); \
    GLOAD(gB0 + ks_, bB_ + off0); \
    GLOAD(gB1 + ks_, bB_ + off0 + 8192); \
  } while (0)

#define DS_BFR(buf, kh) do { \
    const short* Bb_ = (const short*)(smem + 65536 + (buf) * 32768 + (kh) * 16384); \
    _Pragma("unroll") \
    for (int ni = 0; ni < 4; ++ni) \
      bfr[ni] = *(const bf16x8*)(Bb_ + (wc * 64 + ni * 16 + fr) * 32 + fko); \
  } while (0)

#define DS_AF(buf, kh, mh) do { \
    const short* Ab_ = (const short*)(smem + (buf) * 32768 + (kh) * 16384); \
    _Pragma("unroll") \
    for (int mi = 0; mi < 4; ++mi) \
      af[mi] = *(const bf16x8*)(Ab_ + (wr * 128 + ((mh) * 4 + mi) * 16 + fr) * 32 + fko); \
  } while (0)

  // swapped operands: acc[mi][ni] = C^T fragment
  // value(lane,reg) = C[row = mi*16+(lane&15)][col = ni*16+(lane>>4)*4+reg]
#define MFMA16(mh) do { \
    __builtin_amdgcn_s_setprio(1); \
    _Pragma("unroll") \
    for (int mi = 0; mi < 4; ++mi) \
      _Pragma("unroll") \
      for (int ni = 0; ni < 4; ++ni) \
        acc[(mh) * 4 + mi][ni] = __builtin_amdgcn_mfma_f32_16x16x32_bf16( \
            bfr[ni], af[mi], acc[(mh) * 4 + mi][ni], 0, 0, 0); \
    __builtin_amdgcn_s_setprio(0); \
  } while (0)

#define BAR() __builtin_amdgcn_s_barrier()
#define LGKM0() asm volatile("s_waitcnt lgkmcnt(0)" ::: "memory")
#define WCNT(s) asm volatile("s_waitcnt " s ::: "memory")

  // One K-tile = 4 phases. Stages: ph0 -> kh1(tile k+1); ph2 -> kh0(tile k+2).
  // vmcnt(V1) at ph1-end covers kh1(k); vmcnt(V3) at ph3-end covers kh0(k+1).
#define ITER(kk, DO_S0, DO_S2, V1, V3) do { \
    int b_ = (kk) & 1; \
    bf16x8 af[4], bfr[4]; \
    /* ph0: quadrant (mh0, kh0) */ \
    if (DO_S0) STAGE_HALF(((kk) + 1) & 1, (kk) + 1, 1); \
    DS_BFR(b_, 0); DS_AF(b_, 0, 0); \
    BAR(); LGKM0(); \
    MFMA16(0); \
    BAR(); \
    /* ph1: quadrant (mh1, kh0) */ \
    DS_AF(b_, 0, 1); \
    BAR(); LGKM0(); \
    MFMA16(1); \
    WCNT(V1); BAR(); \
    /* ph2: quadrant (mh0, kh1) */ \
    if (DO_S2) STAGE_HALF(b_, (kk) + 2, 0); \
    DS_BFR(b_, 1); DS_AF(b_, 1, 0); \
    BAR(); LGKM0(); \
    MFMA16(0); \
    BAR(); \
    /* ph3: quadrant (mh1, kh1) */ \
    DS_AF(b_, 1, 1); \
    BAR(); LGKM0(); \
    MFMA16(1); \
    WCNT(V3); BAR(); \
  } while (0)

  // prologue: kh0(0), kh1(0), kh0(1) in flight (12); retire kh0(0)
  STAGE_HALF(0, 0, 0);
  STAGE_HALF(0, 0, 1);
  STAGE_HALF(1, 1, 0);
  WCNT("vmcnt(8)");
  BAR();

  #pragma unroll 1
  for (int kt = 0; kt < 6; ++kt)
    ITER(kt, true, true, "vmcnt(8)", "vmcnt(8)");
  ITER(6, true, false, "vmcnt(8)", "vmcnt(4)");
  ITER(7, false, false, "vmcnt(0)", "vmcnt(0)");

  // ---- epilogue: bias + relu + csum; padded-LDS repack -> coalesced stores
  const int cr = lane & 15;            // output row within 16-frag
  const int cg = (lane >> 4) * 4;      // output col base within 16-frag
  float4 bias4[4];
  #pragma unroll
  for (int ni = 0; ni < 4; ++ni)
    bias4[ni] = *(const float4*)(b1 + bcol + wc * 64 + ni * 16 + cg);

  float cl[4][4];
  #pragma unroll
  for (int ni = 0; ni < 4; ++ni)
    #pragma unroll
    for (int r = 0; r < 4; ++r)
      cl[ni][r] = 0.f;

  short* pk = (short*)smem;            // [128][264] shorts = 67584 B (fits 128 KB)
  #pragma unroll 1
  for (int half = 0; half < 2; ++half) {
    __syncthreads();                   // K-loop reads / prev half's stores done
    if (wr == half) {                  // owning waves write their 128 rows
      #pragma unroll
      for (int mi = 0; mi < 8; ++mi) {
        int lrow = mi * 16 + cr;       // 0..127 within half
        #pragma unroll
        for (int ni = 0; ni < 4; ++ni) {
          float v0 = fmaxf(acc[mi][ni][0] + bias4[ni].x, 0.f);
          float v1 = fmaxf(acc[mi][ni][1] + bias4[ni].y, 0.f);
          float v2 = fmaxf(acc[mi][ni][2] + bias4[ni].z, 0.f);
          float v3 = fmaxf(acc[mi][ni][3] + bias4[ni].w, 0.f);
          cl[ni][0] += v0; cl[ni][1] += v1; cl[ni][2] += v2; cl[ni][3] += v3;
          short4 o;
          o.x = f2b(v0); o.y = f2b(v1); o.z = f2b(v2); o.w = f2b(v3);
          *(short4*)(pk + lrow * 264 + wc * 64 + ni * 16 + cg) = o;
        }
      }
    }
    __syncthreads();
    // all 8 waves store 64 KB: 128 rows x 512 B, fully coalesced b128
    #pragma unroll
    for (int i = 0; i < 8; ++i) {
      int c = tid + i * 512;           // 0..4095 chunks of 16 B
      int row = c >> 5, ch = c & 31;
      bf16x8 vv = *(const bf16x8*)(pk + row * 264 + ch * 8);
      *(bf16x8*)(Aout + (size_t)(brow + half * 128 + row) * HID + bcol + ch * 8) = vv;
    }
  }

  // column sums: reduce over the 16 rows (lanes sharing lane>>4)
  #pragma unroll
  for (int ni = 0; ni < 4; ++ni)
    #pragma unroll
    for (int r = 0; r < 4; ++r) {
      #pragma unroll
      for (int m = 1; m < 16; m <<= 1)
        cl[ni][r] += __shfl_xor(cl[ni][r], m);
    }
  if (cr == 0) {                       // 4 lanes/wave; wr=0/1 -> 2-way contention
    #pragma unroll
    for (int ni = 0; ni < 4; ++ni)
      #pragma unroll
      for (int r = 0; r < 4; ++r)
        atomicAdd(&csum[wc * 64 + ni * 16 + cg + r], cl[ni][r]);
  }
  __syncthreads();
  if (tid < 256) atomicAdd(&colsum[bcol + tid], csum[tid]);
}

// ---- K2/K5: vout[col] += sum_i vin[i] * W[i][col]  (W: [4096][4096] fp32) ----
__global__ __launch_bounds__(256) void k_gemv_at(const float* __restrict__ W,
                                                 const float* __restrict__ vin,
                                                 float* __restrict__ vout) {
  const int col = blockIdx.x * 1024 + threadIdx.x * 4;
  const int r0  = blockIdx.y * 64;
  float4 accv = {0.f, 0.f, 0.f, 0.f};
  const float* base = W + (size_t)r0 * HID + col;
  #pragma unroll 16
  for (int i = 0; i < 64; ++i) {
    float vi = vin[r0 + i];
    float4 wv = *(const float4*)(base + (size_t)i * HID);
    accv.x += vi * wv.x; accv.y += vi * wv.y;
    accv.z += vi * wv.z; accv.w += vi * wv.w;
  }
  atomicAdd(&vout[col + 0], accv.x);
  atomicAdd(&vout[col + 1], accv.y);
  atomicAdd(&vout[col + 2], accv.z);
  atomicAdd(&vout[col + 3], accv.w);
}

// ---- K3: t[row] = W2[row,:] . s ; extra block computes beta = b2 . s ----
__global__ __launch_bounds__(256) void k_gemv_row(const float* __restrict__ W,
                                                  const float* __restrict__ vin,
                                                  const float* __restrict__ b2,
                                                  float* __restrict__ vout,
                                                  float* __restrict__ beta) {
  __shared__ float red[4];
  if (blockIdx.x == HID / 4) {           // beta block
    float p = 0.f;
    for (int j = threadIdx.x; j < HID; j += 256) p += b2[j] * vin[j];
    #pragma unroll
    for (int o = 32; o > 0; o >>= 1) p += __shfl_down(p, o);
    int lane = threadIdx.x & 63, w = threadIdx.x >> 6;
    if (lane == 0) red[w] = p;
    __syncthreads();
    if (threadIdx.x == 0) beta[0] = red[0] + red[1] + red[2] + red[3];
    return;
  }
  int w = threadIdx.x >> 6, lane = threadIdx.x & 63;
  int row = blockIdx.x * 4 + w;
  const float* base = W + (size_t)row * HID;
  float p = 0.f;
  #pragma unroll 8
  for (int j = lane * 4; j < HID; j += 256) {
    float4 wv = *(const float4*)(base + j);
    float4 sv = *(const float4*)(vin + j);
    p += wv.x * sv.x + wv.y * sv.y + wv.z * sv.z + wv.w * sv.w;
  }
  #pragma unroll
  for (int o = 32; o > 0; o >>= 1) p += __shfl_down(p, o);
  if (lane == 0) vout[row] = p;
}

// ---- K4: kv[row] = A[row,:] . t + beta   (A bf16) ----
__global__ __launch_bounds__(256) void k_kv(const short* __restrict__ A,
                                            const float* __restrict__ t,
                                            const float* __restrict__ beta,
                                            float* __restrict__ kv) {
  int w = threadIdx.x >> 6, lane = threadIdx.x & 63;
  int row = blockIdx.x * 4 + w;
  const short* base = A + (size_t)row * HID;
  float p = 0.f;
  #pragma unroll
  for (int j = lane * 8; j < HID; j += 512) {
    bf16x8 av = *(const bf16x8*)(base + j);
    float4 t0 = *(const float4*)(t + j);
    float4 t1 = *(const float4*)(t + j + 4);
    p += b2f(av[0]) * t0.x + b2f(av[1]) * t0.y + b2f(av[2]) * t0.z + b2f(av[3]) * t0.w
       + b2f(av[4]) * t1.x + b2f(av[5]) * t1.y + b2f(av[6]) * t1.z + b2f(av[7]) * t1.w;
  }
  #pragma unroll
  for (int o = 32; o > 0; o >>= 1) p += __shfl_down(p, o);
  if (lane == 0) kv[row] = p + beta[0];
}

// ---- K6: out = relu(uacc) . W4 + b4 ----
__global__ __launch_bounds__(256) void k_final(const float* __restrict__ uacc,
                                               const float* __restrict__ W4,
                                               const float* __restrict__ b4,
                                               float* __restrict__ out) {
  __shared__ float red[4];
  float p = 0.f;
  for (int j = threadIdx.x; j < HID; j += 256) {
    float uv = uacc[j];
    uv = uv > 0.f ? uv : 0.f;
    p += uv * W4[j];
  }
  #pragma unroll
  for (int o = 32; o > 0; o >>= 1) p += __shfl_down(p, o);
  int lane = threadIdx.x & 63, w = threadIdx.x >> 6;
  if (lane == 0) red[w] = p;
  __syncthreads();
  if (threadIdx.x == 0) out[0] = red[0] + red[1] + red[2] + red[3] + b4[0];
}

extern "C" void kernel_launch(void* const* d_in, const int* in_sizes, int n_in,
                              void* d_out, int out_size, void* d_ws, size_t ws_size,
                              hipStream_t stream) {
  const float* x  = (const float*)d_in[0];
  // d_in[1] = edge_index (dead in the reference)
  const float* W1 = (const float*)d_in[2];
  const float* b1 = (const float*)d_in[3];
  const float* W2 = (const float*)d_in[4];
  const float* b2 = (const float*)d_in[5];
  const float* W3 = (const float*)d_in[6];
  const float* b3 = (const float*)d_in[7];
  const float* W4 = (const float*)d_in[8];
  const float* b4 = (const float*)d_in[9];
  float* out = (float*)d_out;

  char* ws = (char*)d_ws;
  short* Abf  = (short*)(ws);                 // 32 MB
  short* xb   = (short*)(ws + 33554432);      // 4 MB
  short* w1t  = (short*)(ws + 37748736);      // 4 MB
  float* aacc = (float*)(ws + 41943040);
  float* svec = (float*)(ws + 41959424);
  float* tvec = (float*)(ws + 41975808);
  float* kvv  = (float*)(ws + 41992192);
  float* uacc = (float*)(ws + 42008576);
  float* beta = (float*)(ws + 42024960);

  k_prep    <<<dim3(4112),     dim3(256), 0, stream>>>(x, W1, b2, b3, xb, w1t, aacc, svec, uacc);
  k_gemm1   <<<dim3(256),      dim3(512), 131072, stream>>>(xb, w1t, b1, Abf, aacc);
  k_gemv_at <<<dim3(4, 64),    dim3(256), 0, stream>>>(W2, aacc, svec);
  k_gemv_row<<<dim3(1025),     dim3(256), 0, stream>>>(W2, svec, b2, tvec, beta);
  k_kv      <<<dim3(1024),     dim3(256), 0, stream>>>(Abf, tvec, beta, kvv);
  k_gemv_at <<<dim3(4, 64),    dim3(256), 0, stream>>>(W3, kvv, uacc);
  k_final   <<<dim3(1),        dim3(256), 0, stream>>>(uacc, W4, b4, out);
}